// Round 1
// baseline (3882.154 us; speedup 1.0000x reference)
//
#include <hip/hip_runtime.h>
#include <hip/hip_bf16.h>

#define SVC   50000
#define INST  100000
#define NODE  50000
#define FDIM  128
#define HDIM  128
#define OUTD  256
#define E_SC  400000
#define E_IN  100000
#define E_NI  100000
#define E_II  800000
#define NTOT  (SVC + NODE + INST)   // 200000
#define KTOT  NTOT

// ---------------- degree count ----------------
__global__ void k_deg(const int* __restrict__ src, const int* __restrict__ dst,
                      int* __restrict__ dout, int* __restrict__ din, int E) {
    int t = blockIdx.x * blockDim.x + threadIdx.x;
    if (t >= E) return;
    atomicAdd(&dout[src[t]], 1);
    atomicAdd(&din[dst[t]], 1);
}

// ---------------- deg -> rsqrt(max(deg,1)) ----------------
__global__ void k_norm(const int* __restrict__ deg, float* __restrict__ nrm, int n) {
    int t = blockIdx.x * blockDim.x + threadIdx.x;
    if (t >= n) return;
    float d = (float)deg[t];
    nrm[t] = rsqrtf(d > 1.f ? d : 1.f);
}

// ---------------- scatter: agg[dst] += feat[src] * ns[src] * nd[dst] ----------------
// 32 threads per edge, 4 floats each
__global__ void k_scatter(const float* __restrict__ feat,
                          const int* __restrict__ src, const int* __restrict__ dst,
                          const float* __restrict__ ns, const float* __restrict__ nd,
                          float* __restrict__ agg, int E) {
    int t = blockIdx.x * blockDim.x + threadIdx.x;
    int e = t >> 5;
    if (e >= E) return;
    int lane = t & 31;
    int s = src[e], d = dst[e];
    float scale = ns[s] * nd[d];
    const float4 v = *reinterpret_cast<const float4*>(feat + (size_t)s * FDIM + lane * 4);
    float* p = agg + (size_t)d * FDIM + lane * 4;
    atomicAdd(p + 0, v.x * scale);
    atomicAdd(p + 1, v.y * scale);
    atomicAdd(p + 2, v.z * scale);
    atomicAdd(p + 3, v.w * scale);
}

// ---------------- projection: out = lrelu(A0 @ W0 (+ A1 @ W1) + b) , in-place safe ----------------
// 64 rows/block, 256 threads, k-sliced (32) staging; thread tile 4 rows x 8 cols
template <bool DUAL>
__global__ __launch_bounds__(256) void k_proj(
    const float* __restrict__ A0, const float* __restrict__ W0, const float* __restrict__ b0,
    const float* __restrict__ A1, const float* __restrict__ W1, const float* __restrict__ b1,
    float* __restrict__ out, int nrows) {
    __shared__ float xs0[64][36];           // [row][k-slice], padded (36 = 16B-aligned rows, bank-spread)
    __shared__ float ws0[32][128];          // [k][c]
    __shared__ float xs1[DUAL ? 64 : 1][36];
    __shared__ float ws1[DUAL ? 32 : 1][128];

    const int t  = threadIdx.x;
    const int tc = t & 15;          // c0 = tc*8
    const int tr = t >> 4;          // rows tr*4 .. tr*4+3
    const int rowbase = blockIdx.x * 64;

    float acc[4][8];
#pragma unroll
    for (int i = 0; i < 4; i++)
#pragma unroll
        for (int j = 0; j < 8; j++) acc[i][j] = 0.f;

    for (int k0 = 0; k0 < FDIM; k0 += 32) {
        __syncthreads();
        // stage W slice (32x128)
#pragma unroll
        for (int p = 0; p < 4; p++) {
            int f4 = t + p * 256;           // 0..1023
            int kr = f4 >> 5, c4 = f4 & 31;
            *reinterpret_cast<float4*>(&ws0[kr][c4 * 4]) =
                *reinterpret_cast<const float4*>(W0 + (size_t)(k0 + kr) * HDIM + c4 * 4);
            if constexpr (DUAL) {
                *reinterpret_cast<float4*>(&ws1[kr][c4 * 4]) =
                    *reinterpret_cast<const float4*>(W1 + (size_t)(k0 + kr) * HDIM + c4 * 4);
            }
        }
        // stage x slice (64 rows x 32 k)
#pragma unroll
        for (int p = 0; p < 2; p++) {
            int f4 = t + p * 256;           // 0..511
            int r = f4 >> 3, kq = f4 & 7;
            int gr = rowbase + r;
            float4 v = make_float4(0.f, 0.f, 0.f, 0.f);
            if (gr < nrows) v = *reinterpret_cast<const float4*>(A0 + (size_t)gr * FDIM + k0 + kq * 4);
            *reinterpret_cast<float4*>(&xs0[r][kq * 4]) = v;
            if constexpr (DUAL) {
                float4 v1 = make_float4(0.f, 0.f, 0.f, 0.f);
                if (gr < nrows) v1 = *reinterpret_cast<const float4*>(A1 + (size_t)gr * FDIM + k0 + kq * 4);
                *reinterpret_cast<float4*>(&xs1[r][kq * 4]) = v1;
            }
        }
        __syncthreads();
#pragma unroll
        for (int kk = 0; kk < 32; kk++) {
            float wv[8];
            *reinterpret_cast<float4*>(&wv[0]) = *reinterpret_cast<const float4*>(&ws0[kk][tc * 8]);
            *reinterpret_cast<float4*>(&wv[4]) = *reinterpret_cast<const float4*>(&ws0[kk][tc * 8 + 4]);
            float xv[4];
#pragma unroll
            for (int i = 0; i < 4; i++) xv[i] = xs0[tr * 4 + i][kk];
#pragma unroll
            for (int i = 0; i < 4; i++)
#pragma unroll
                for (int j = 0; j < 8; j++) acc[i][j] = fmaf(xv[i], wv[j], acc[i][j]);
            if constexpr (DUAL) {
                float wv1[8];
                *reinterpret_cast<float4*>(&wv1[0]) = *reinterpret_cast<const float4*>(&ws1[kk][tc * 8]);
                *reinterpret_cast<float4*>(&wv1[4]) = *reinterpret_cast<const float4*>(&ws1[kk][tc * 8 + 4]);
                float xv1[4];
#pragma unroll
                for (int i = 0; i < 4; i++) xv1[i] = xs1[tr * 4 + i][kk];
#pragma unroll
                for (int i = 0; i < 4; i++)
#pragma unroll
                    for (int j = 0; j < 8; j++) acc[i][j] = fmaf(xv1[i], wv1[j], acc[i][j]);
            }
        }
    }
    // epilogue: + bias, leaky_relu, store (in-place safe: all global reads done before last barrier)
    float bb[8];
#pragma unroll
    for (int j = 0; j < 8; j++) {
        bb[j] = b0[tc * 8 + j];
        if constexpr (DUAL) bb[j] += b1[tc * 8 + j];
    }
#pragma unroll
    for (int i = 0; i < 4; i++) {
        int gr = rowbase + tr * 4 + i;
        if (gr < nrows) {
            float o[8];
#pragma unroll
            for (int j = 0; j < 8; j++) {
                float v = acc[i][j] + bb[j];
                o[j] = v > 0.f ? v : 0.01f * v;
            }
            float* dstp = out + (size_t)gr * HDIM + tc * 8;
            *reinterpret_cast<float4*>(dstp)     = *reinterpret_cast<const float4*>(&o[0]);
            *reinterpret_cast<float4*>(dstp + 4) = *reinterpret_cast<const float4*>(&o[4]);
        }
    }
}

// ---------------- final GEMM: oacc[256][128] += Wt[256][200000] @ act[200000][128] (split-K) ----------------
#define GK 256
__global__ __launch_bounds__(512) void k_gemm(const float* __restrict__ act,
                                              const float* __restrict__ Wt,
                                              float* __restrict__ oacc) {
    __shared__ float wsm[32][257];   // [kk][o], +1 pad -> conflict-free stage writes
    __shared__ float asm_[32][128];  // [kk][j]

    const int t  = threadIdx.x;
    const int tj = t & 15;           // j0 = tj*8
    const int to = t >> 4;           // o0 = to*8  (0..31)
    const int k0b = blockIdx.x * GK;

    float acc[8][8];
#pragma unroll
    for (int i = 0; i < 8; i++)
#pragma unroll
        for (int j = 0; j < 8; j++) acc[i][j] = 0.f;

    for (int kc = 0; kc < GK; kc += 32) {
        int k0 = k0b + kc;
        __syncthreads();
        // stage W_tot chunk: 256 o x 32 k
#pragma unroll
        for (int p = 0; p < 4; p++) {
            int f4 = t + p * 512;        // 0..2047
            int o = f4 >> 3, kq = f4 & 7;
            float4 v = make_float4(0.f, 0.f, 0.f, 0.f);
            if (k0 + kq * 4 < KTOT)
                v = *reinterpret_cast<const float4*>(Wt + (size_t)o * KTOT + k0 + kq * 4);
            wsm[kq * 4 + 0][o] = v.x;
            wsm[kq * 4 + 1][o] = v.y;
            wsm[kq * 4 + 2][o] = v.z;
            wsm[kq * 4 + 3][o] = v.w;
        }
        // stage act chunk: 32 k x 128 j
#pragma unroll
        for (int p = 0; p < 2; p++) {
            int f4 = t + p * 512;        // 0..1023
            int kk = f4 >> 5, j4 = f4 & 31;
            float4 v = make_float4(0.f, 0.f, 0.f, 0.f);
            if (k0 + kk < KTOT)
                v = *reinterpret_cast<const float4*>(act + (size_t)(k0 + kk) * HDIM + j4 * 4);
            *reinterpret_cast<float4*>(&asm_[kk][j4 * 4]) = v;
        }
        __syncthreads();
#pragma unroll
        for (int kk = 0; kk < 32; kk++) {
            float av[8];
            *reinterpret_cast<float4*>(&av[0]) = *reinterpret_cast<const float4*>(&asm_[kk][tj * 8]);
            *reinterpret_cast<float4*>(&av[4]) = *reinterpret_cast<const float4*>(&asm_[kk][tj * 8 + 4]);
            float wv[8];
#pragma unroll
            for (int i = 0; i < 8; i++) wv[i] = wsm[kk][to * 8 + i];
#pragma unroll
            for (int i = 0; i < 8; i++)
#pragma unroll
                for (int j = 0; j < 8; j++) acc[i][j] = fmaf(wv[i], av[j], acc[i][j]);
        }
    }
#pragma unroll
    for (int i = 0; i < 8; i++)
#pragma unroll
        for (int j = 0; j < 8; j++)
            atomicAdd(&oacc[(size_t)(to * 8 + i) * HDIM + tj * 8 + j], acc[i][j]);
}

__global__ void k_bias(const float* __restrict__ oacc, const float* __restrict__ bt,
                       float* __restrict__ out) {
    int i = blockIdx.x * blockDim.x + threadIdx.x;
    if (i < OUTD * HDIM) out[i] = oacc[i] + bt[i >> 7];
}

// ---------------- launch ----------------
extern "C" void kernel_launch(void* const* d_in, const int* in_sizes, int n_in,
                              void* d_out, int out_size, void* d_ws, size_t ws_size,
                              hipStream_t stream) {
    const float* feat_svc  = (const float*)d_in[0];
    const float* feat_inst = (const float*)d_in[1];
    const float* feat_node = (const float*)d_in[2];
    const int* svc_src = (const int*)d_in[3];
    const int* svc_dst = (const int*)d_in[4];
    const int* in_src  = (const int*)d_in[5];
    const int* in_dst  = (const int*)d_in[6];
    const int* ni_src  = (const int*)d_in[7];
    const int* ni_dst  = (const int*)d_in[8];
    const int* ii_src  = (const int*)d_in[9];
    const int* ii_dst  = (const int*)d_in[10];
    const float* W_sc = (const float*)d_in[11];
    const float* b_sc = (const float*)d_in[12];
    const float* W_in = (const float*)d_in[13];
    const float* b_in = (const float*)d_in[14];
    const float* W_ni = (const float*)d_in[15];
    const float* b_ni = (const float*)d_in[16];
    const float* W_ii = (const float*)d_in[17];
    const float* b_ii = (const float*)d_in[18];
    const float* W_tot = (const float*)d_in[19];
    const float* b_tot = (const float*)d_in[20];
    float* out = (float*)d_out;

    // ws layout:
    //   deg    : int  [600000]                 @ 0
    //   nrm    : float[600000]                 @ 2,400,000
    //   aggraw : float[300000*128]             @ 4,800,000      (153.6 MB)
    //   oacc   : float[256*128]                @ 158,400,000
    char* ws = (char*)d_ws;
    int*   deg    = (int*)ws;
    float* nrm    = (float*)(ws + 2400000);
    float* aggraw = (float*)(ws + 4800000);
    float* oacc   = (float*)(ws + 4800000 + 153600000ULL);

    // degree norm array element offsets within deg/nrm:
    //  sc_out 0 | sc_in 50000 | in_out 100000 | in_in 200000 |
    //  ni_out 250000 | ni_in 300000 | ii_out 400000 | ii_in 500000
    hipMemsetAsync(deg, 0, 2400000, stream);
    hipMemsetAsync(aggraw, 0, 153600000ULL + 131072ULL, stream);  // aggraw + oacc

    k_deg<<<(E_SC + 255) / 256, 256, 0, stream>>>(svc_src, svc_dst, deg + 0,      deg + 50000,  E_SC);
    k_deg<<<(E_IN + 255) / 256, 256, 0, stream>>>(in_src,  in_dst,  deg + 100000, deg + 200000, E_IN);
    k_deg<<<(E_NI + 255) / 256, 256, 0, stream>>>(ni_src,  ni_dst,  deg + 250000, deg + 300000, E_NI);
    k_deg<<<(E_II + 255) / 256, 256, 0, stream>>>(ii_src,  ii_dst,  deg + 400000, deg + 500000, E_II);
    k_norm<<<(600000 + 255) / 256, 256, 0, stream>>>(deg, nrm, 600000);

    // aggraw row regions: sc @0 (50000) | in @50000 (50000) | ni @100000 (100000) | ii @200000 (100000)
    k_scatter<<<((size_t)E_SC * 32 + 255) / 256, 256, 0, stream>>>(
        feat_svc, svc_src, svc_dst, nrm + 0, nrm + 50000, aggraw, E_SC);
    k_scatter<<<((size_t)E_IN * 32 + 255) / 256, 256, 0, stream>>>(
        feat_inst, in_src, in_dst, nrm + 100000, nrm + 200000, aggraw + (size_t)50000 * 128, E_IN);
    k_scatter<<<((size_t)E_NI * 32 + 255) / 256, 256, 0, stream>>>(
        feat_node, ni_src, ni_dst, nrm + 250000, nrm + 300000, aggraw + (size_t)100000 * 128, E_NI);
    k_scatter<<<((size_t)E_II * 32 + 255) / 256, 256, 0, stream>>>(
        feat_inst, ii_src, ii_dst, nrm + 400000, nrm + 500000, aggraw + (size_t)200000 * 128, E_II);

    // act (in-place over aggraw rows 0..200000): lrelu(aggraw @ W + b)
    k_proj<false><<<(SVC + 63) / 64, 256, 0, stream>>>(
        aggraw, W_sc, b_sc, nullptr, nullptr, nullptr, aggraw, SVC);
    k_proj<false><<<(NODE + 63) / 64, 256, 0, stream>>>(
        aggraw + (size_t)50000 * 128, W_in, b_in, nullptr, nullptr, nullptr,
        aggraw + (size_t)50000 * 128, NODE);
    k_proj<true><<<(INST + 63) / 64, 256, 0, stream>>>(
        aggraw + (size_t)100000 * 128, W_ni, b_ni,
        aggraw + (size_t)200000 * 128, W_ii, b_ii,
        aggraw + (size_t)100000 * 128, INST);

    // out = W_tot @ act + b_tot
    k_gemm<<<(KTOT + GK - 1) / GK, 512, 0, stream>>>(aggraw, W_tot, oacc);
    k_bias<<<128, 256, 0, stream>>>(oacc, b_tot, out);
}

// Round 2
// 1829.442 us; speedup vs baseline: 2.1220x; 2.1220x over previous
//
#include <hip/hip_runtime.h>
#include <hip/hip_bf16.h>

#define SVC   50000
#define INST  100000
#define NODE  50000
#define FDIM  128
#define HDIM  128
#define OUTD  256
#define E_SC  400000
#define E_IN  100000
#define E_NI  100000
#define E_II  800000
#define NTOT  (SVC + NODE + INST)   // 200000
#define KTOT  NTOT
#define NDST  300000                // concatenated dst slots: sc 50k | in 50k | ni 100k | ii 100k
#define NB    ((NDST + 255) / 256)  // 1172 scan blocks
#define ETOT  (E_SC + E_IN + E_NI + E_II)  // 1.4M

// ---------------- degree count ----------------
__global__ void k_deg(const int* __restrict__ src, const int* __restrict__ dst,
                      int* __restrict__ dout, int* __restrict__ din, int E) {
    int t = blockIdx.x * blockDim.x + threadIdx.x;
    if (t >= E) return;
    atomicAdd(&dout[src[t]], 1);
    atomicAdd(&din[dst[t]], 1);
}

// ---------------- deg -> rsqrt(max(deg,1)) ----------------
__global__ void k_norm(const int* __restrict__ deg, float* __restrict__ nrm, int n) {
    int t = blockIdx.x * blockDim.x + threadIdx.x;
    if (t >= n) return;
    float d = (float)deg[t];
    nrm[t] = rsqrtf(d > 1.f ? d : 1.f);
}

// ---------------- scan stage 1: per-block sums of din[0..n) ----------------
__global__ void k_bsum(const int* __restrict__ din, int* __restrict__ bsum, int n) {
    __shared__ int sm[256];
    int i = blockIdx.x * 256 + threadIdx.x;
    sm[threadIdx.x] = (i < n) ? din[i] : 0;
    __syncthreads();
#pragma unroll
    for (int s = 128; s > 0; s >>= 1) {
        if (threadIdx.x < s) sm[threadIdx.x] += sm[threadIdx.x + s];
        __syncthreads();
    }
    if (threadIdx.x == 0) bsum[blockIdx.x] = sm[0];
}

// ---------------- scan stage 2: single-block exclusive scan of block sums ----------------
__global__ __launch_bounds__(1024) void k_btop(const int* __restrict__ bsum,
                                               int* __restrict__ boff, int nb) {
    __shared__ int sm[1024];
    int carry = 0;
    for (int c = 0; c < 2; c++) {
        int i = c * 1024 + threadIdx.x;
        int v = (i < nb) ? bsum[i] : 0;
        sm[threadIdx.x] = v;
        __syncthreads();
        for (int s = 1; s < 1024; s <<= 1) {
            int add = (threadIdx.x >= (unsigned)s) ? sm[threadIdx.x - s] : 0;
            __syncthreads();
            sm[threadIdx.x] += add;
            __syncthreads();
        }
        if (i < nb) boff[i] = carry + sm[threadIdx.x] - v;
        carry += sm[1023];
        __syncthreads();
    }
}

// ---------------- scan stage 3: add-back, write off[] and running cursors cur[] ----------------
__global__ void k_off(const int* __restrict__ din, const int* __restrict__ boff,
                      int* __restrict__ off, int* __restrict__ cur, int n) {
    __shared__ int sm[256];
    int i = blockIdx.x * 256 + threadIdx.x;
    int v = (i < n) ? din[i] : 0;
    sm[threadIdx.x] = v;
    __syncthreads();
#pragma unroll
    for (int s = 1; s < 256; s <<= 1) {
        int add = (threadIdx.x >= (unsigned)s) ? sm[threadIdx.x - s] : 0;
        __syncthreads();
        sm[threadIdx.x] += add;
        __syncthreads();
    }
    if (i < n) {
        int o = boff[blockIdx.x] + sm[threadIdx.x] - v;
        off[i] = o;
        cur[i] = o;
    }
    if (i == 0) off[n] = ETOT;
}

// ---------------- bin edges by dst: esrc[slot] = src ----------------
__global__ void k_bin(const int* __restrict__ src, const int* __restrict__ dst,
                      int* __restrict__ cur, int* __restrict__ esrc, int E) {
    int t = blockIdx.x * blockDim.x + threadIdx.x;
    if (t >= E) return;
    int pos = atomicAdd(&cur[dst[t]], 1);
    esrc[pos] = src[t];
}

// ---------------- gather: agg[r] = nd[r] * sum_e feat[esrc[e]] * ns[esrc[e]] ----------------
// one wave (64 lanes) per dst row; lane owns 2 of the 128 columns
__global__ __launch_bounds__(256) void k_gather(const float* __restrict__ feat,
                                                const int* __restrict__ esrc,
                                                const int* __restrict__ off,
                                                const float* __restrict__ ns,
                                                const float* __restrict__ ndv,
                                                float* __restrict__ agg, int nrows) {
    int wid = (blockIdx.x * 256 + threadIdx.x) >> 6;
    if (wid >= nrows) return;
    int lane = threadIdx.x & 63;
    int e0 = off[wid], e1 = off[wid + 1];
    float ax = 0.f, ay = 0.f;
    for (int e = e0; e < e1; e++) {
        int s = esrc[e];
        float sc = ns[s];
        float2 v = *reinterpret_cast<const float2*>(feat + (size_t)s * FDIM + lane * 2);
        ax = fmaf(v.x, sc, ax);
        ay = fmaf(v.y, sc, ay);
    }
    float nv = ndv[wid];
    *reinterpret_cast<float2*>(agg + (size_t)wid * FDIM + lane * 2) = make_float2(ax * nv, ay * nv);
}

// ---------------- projection: out = lrelu(A0 @ W0 (+ A1 @ W1) + b) , in-place safe ----------------
template <bool DUAL>
__global__ __launch_bounds__(256) void k_proj(
    const float* __restrict__ A0, const float* __restrict__ W0, const float* __restrict__ b0,
    const float* __restrict__ A1, const float* __restrict__ W1, const float* __restrict__ b1,
    float* __restrict__ out, int nrows) {
    __shared__ float xs0[64][36];
    __shared__ float ws0[32][128];
    __shared__ float xs1[DUAL ? 64 : 1][36];
    __shared__ float ws1[DUAL ? 32 : 1][128];

    const int t  = threadIdx.x;
    const int tc = t & 15;
    const int tr = t >> 4;
    const int rowbase = blockIdx.x * 64;

    float acc[4][8];
#pragma unroll
    for (int i = 0; i < 4; i++)
#pragma unroll
        for (int j = 0; j < 8; j++) acc[i][j] = 0.f;

    for (int k0 = 0; k0 < FDIM; k0 += 32) {
        __syncthreads();
#pragma unroll
        for (int p = 0; p < 4; p++) {
            int f4 = t + p * 256;
            int kr = f4 >> 5, c4 = f4 & 31;
            *reinterpret_cast<float4*>(&ws0[kr][c4 * 4]) =
                *reinterpret_cast<const float4*>(W0 + (size_t)(k0 + kr) * HDIM + c4 * 4);
            if constexpr (DUAL) {
                *reinterpret_cast<float4*>(&ws1[kr][c4 * 4]) =
                    *reinterpret_cast<const float4*>(W1 + (size_t)(k0 + kr) * HDIM + c4 * 4);
            }
        }
#pragma unroll
        for (int p = 0; p < 2; p++) {
            int f4 = t + p * 256;
            int r = f4 >> 3, kq = f4 & 7;
            int gr = rowbase + r;
            float4 v = make_float4(0.f, 0.f, 0.f, 0.f);
            if (gr < nrows) v = *reinterpret_cast<const float4*>(A0 + (size_t)gr * FDIM + k0 + kq * 4);
            *reinterpret_cast<float4*>(&xs0[r][kq * 4]) = v;
            if constexpr (DUAL) {
                float4 v1 = make_float4(0.f, 0.f, 0.f, 0.f);
                if (gr < nrows) v1 = *reinterpret_cast<const float4*>(A1 + (size_t)gr * FDIM + k0 + kq * 4);
                *reinterpret_cast<float4*>(&xs1[r][kq * 4]) = v1;
            }
        }
        __syncthreads();
#pragma unroll
        for (int kk = 0; kk < 32; kk++) {
            float wv[8];
            *reinterpret_cast<float4*>(&wv[0]) = *reinterpret_cast<const float4*>(&ws0[kk][tc * 8]);
            *reinterpret_cast<float4*>(&wv[4]) = *reinterpret_cast<const float4*>(&ws0[kk][tc * 8 + 4]);
            float xv[4];
#pragma unroll
            for (int i = 0; i < 4; i++) xv[i] = xs0[tr * 4 + i][kk];
#pragma unroll
            for (int i = 0; i < 4; i++)
#pragma unroll
                for (int j = 0; j < 8; j++) acc[i][j] = fmaf(xv[i], wv[j], acc[i][j]);
            if constexpr (DUAL) {
                float wv1[8];
                *reinterpret_cast<float4*>(&wv1[0]) = *reinterpret_cast<const float4*>(&ws1[kk][tc * 8]);
                *reinterpret_cast<float4*>(&wv1[4]) = *reinterpret_cast<const float4*>(&ws1[kk][tc * 8 + 4]);
                float xv1[4];
#pragma unroll
                for (int i = 0; i < 4; i++) xv1[i] = xs1[tr * 4 + i][kk];
#pragma unroll
                for (int i = 0; i < 4; i++)
#pragma unroll
                    for (int j = 0; j < 8; j++) acc[i][j] = fmaf(xv1[i], wv1[j], acc[i][j]);
            }
        }
    }
    float bb[8];
#pragma unroll
    for (int j = 0; j < 8; j++) {
        bb[j] = b0[tc * 8 + j];
        if constexpr (DUAL) bb[j] += b1[tc * 8 + j];
    }
#pragma unroll
    for (int i = 0; i < 4; i++) {
        int gr = rowbase + tr * 4 + i;
        if (gr < nrows) {
            float o[8];
#pragma unroll
            for (int j = 0; j < 8; j++) {
                float v = acc[i][j] + bb[j];
                o[j] = v > 0.f ? v : 0.01f * v;
            }
            float* dstp = out + (size_t)gr * HDIM + tc * 8;
            *reinterpret_cast<float4*>(dstp)     = *reinterpret_cast<const float4*>(&o[0]);
            *reinterpret_cast<float4*>(dstp + 4) = *reinterpret_cast<const float4*>(&o[4]);
        }
    }
}

// ---------------- final GEMM: oacc[256][128] += Wt[256][200000] @ act[200000][128] (split-K) ----------------
#define GK 256
__global__ __launch_bounds__(512) void k_gemm(const float* __restrict__ act,
                                              const float* __restrict__ Wt,
                                              float* __restrict__ oacc) {
    __shared__ float wsm[32][257];
    __shared__ float asm_[32][128];

    const int t  = threadIdx.x;
    const int tj = t & 15;
    const int to = t >> 4;
    const int k0b = blockIdx.x * GK;

    float acc[8][8];
#pragma unroll
    for (int i = 0; i < 8; i++)
#pragma unroll
        for (int j = 0; j < 8; j++) acc[i][j] = 0.f;

    for (int kc = 0; kc < GK; kc += 32) {
        int k0 = k0b + kc;
        __syncthreads();
#pragma unroll
        for (int p = 0; p < 4; p++) {
            int f4 = t + p * 512;
            int o = f4 >> 3, kq = f4 & 7;
            float4 v = make_float4(0.f, 0.f, 0.f, 0.f);
            if (k0 + kq * 4 < KTOT)
                v = *reinterpret_cast<const float4*>(Wt + (size_t)o * KTOT + k0 + kq * 4);
            wsm[kq * 4 + 0][o] = v.x;
            wsm[kq * 4 + 1][o] = v.y;
            wsm[kq * 4 + 2][o] = v.z;
            wsm[kq * 4 + 3][o] = v.w;
        }
#pragma unroll
        for (int p = 0; p < 2; p++) {
            int f4 = t + p * 512;
            int kk = f4 >> 5, j4 = f4 & 31;
            float4 v = make_float4(0.f, 0.f, 0.f, 0.f);
            if (k0 + kk < KTOT)
                v = *reinterpret_cast<const float4*>(act + (size_t)(k0 + kk) * HDIM + j4 * 4);
            *reinterpret_cast<float4*>(&asm_[kk][j4 * 4]) = v;
        }
        __syncthreads();
#pragma unroll
        for (int kk = 0; kk < 32; kk++) {
            float av[8];
            *reinterpret_cast<float4*>(&av[0]) = *reinterpret_cast<const float4*>(&asm_[kk][tj * 8]);
            *reinterpret_cast<float4*>(&av[4]) = *reinterpret_cast<const float4*>(&asm_[kk][tj * 8 + 4]);
            float wv[8];
#pragma unroll
            for (int i = 0; i < 8; i++) wv[i] = wsm[kk][to * 8 + i];
#pragma unroll
            for (int i = 0; i < 8; i++)
#pragma unroll
                for (int j = 0; j < 8; j++) acc[i][j] = fmaf(wv[i], av[j], acc[i][j]);
        }
    }
#pragma unroll
    for (int i = 0; i < 8; i++)
#pragma unroll
        for (int j = 0; j < 8; j++)
            atomicAdd(&oacc[(size_t)(to * 8 + i) * HDIM + tj * 8 + j], acc[i][j]);
}

__global__ void k_bias(const float* __restrict__ oacc, const float* __restrict__ bt,
                       float* __restrict__ out) {
    int i = blockIdx.x * blockDim.x + threadIdx.x;
    if (i < OUTD * HDIM) out[i] = oacc[i] + bt[i >> 7];
}

// ---------------- launch ----------------
extern "C" void kernel_launch(void* const* d_in, const int* in_sizes, int n_in,
                              void* d_out, int out_size, void* d_ws, size_t ws_size,
                              hipStream_t stream) {
    const float* feat_svc  = (const float*)d_in[0];
    const float* feat_inst = (const float*)d_in[1];
    const float* feat_node = (const float*)d_in[2];
    const int* svc_src = (const int*)d_in[3];
    const int* svc_dst = (const int*)d_in[4];
    const int* in_src  = (const int*)d_in[5];
    const int* in_dst  = (const int*)d_in[6];
    const int* ni_src  = (const int*)d_in[7];
    const int* ni_dst  = (const int*)d_in[8];
    const int* ii_src  = (const int*)d_in[9];
    const int* ii_dst  = (const int*)d_in[10];
    const float* W_sc = (const float*)d_in[11];
    const float* b_sc = (const float*)d_in[12];
    const float* W_in = (const float*)d_in[13];
    const float* b_in = (const float*)d_in[14];
    const float* W_ni = (const float*)d_in[15];
    const float* b_ni = (const float*)d_in[16];
    const float* W_ii = (const float*)d_in[17];
    const float* b_ii = (const float*)d_in[18];
    const float* W_tot = (const float*)d_in[19];
    const float* b_tot = (const float*)d_in[20];
    float* out = (float*)d_out;

    // deg/nrm layout (element offsets):
    //   din : sc_in 0 | in_in 50000 | ni_in 100000 | ii_in 200000   (= aggraw row regions)
    //   dout: sc_out 300000 | in_out 350000 | ni_out 450000 | ii_out 500000
    // ws layout (bytes):
    char* ws = (char*)d_ws;
    int*   deg    = (int*)ws;                          // 600000 ints
    float* nrm    = (float*)(ws + 2400000);            // 600000 f
    int*   off    = (int*)(ws + 4800000);              // 300001 ints (+pad)
    int*   cur    = (int*)(ws + 6000128);              // 300000 ints
    int*   bsum   = (int*)(ws + 7200128);              // NB ints
    int*   boff   = (int*)(ws + 7205248);              // NB ints
    int*   esrc   = (int*)(ws + 7210496);              // 1.4M ints
    float* aggraw = (float*)(ws + 12810496);           // 300000*128 f
    float* oacc   = (float*)(ws + 12810496 + 153600000ULL);  // 256*128 f

    hipMemsetAsync(deg, 0, 2400000, stream);
    hipMemsetAsync(oacc, 0, 131072, stream);

    k_deg<<<(E_SC + 255) / 256, 256, 0, stream>>>(svc_src, svc_dst, deg + 300000, deg + 0,      E_SC);
    k_deg<<<(E_IN + 255) / 256, 256, 0, stream>>>(in_src,  in_dst,  deg + 350000, deg + 50000,  E_IN);
    k_deg<<<(E_NI + 255) / 256, 256, 0, stream>>>(ni_src,  ni_dst,  deg + 450000, deg + 100000, E_NI);
    k_deg<<<(E_II + 255) / 256, 256, 0, stream>>>(ii_src,  ii_dst,  deg + 500000, deg + 200000, E_II);
    k_norm<<<(600000 + 255) / 256, 256, 0, stream>>>(deg, nrm, 600000);

    // exclusive scan of the 300k in-degrees -> off[], cur[]
    k_bsum<<<NB, 256, 0, stream>>>(deg, bsum, NDST);
    k_btop<<<1, 1024, 0, stream>>>(bsum, boff, NB);
    k_off<<<NB, 256, 0, stream>>>(deg, boff, off, cur, NDST);

    // bin edge sources into per-dst segments
    k_bin<<<(E_SC + 255) / 256, 256, 0, stream>>>(svc_src, svc_dst, cur + 0,      esrc, E_SC);
    k_bin<<<(E_IN + 255) / 256, 256, 0, stream>>>(in_src,  in_dst,  cur + 50000,  esrc, E_IN);
    k_bin<<<(E_NI + 255) / 256, 256, 0, stream>>>(ni_src,  ni_dst,  cur + 100000, esrc, E_NI);
    k_bin<<<(E_II + 255) / 256, 256, 0, stream>>>(ii_src,  ii_dst,  cur + 200000, esrc, E_II);

    // gather per region (one wave per dst row)
    k_gather<<<(SVC  * 64 + 255) / 256, 256, 0, stream>>>(
        feat_svc,  esrc, off + 0,      nrm + 300000, nrm + 0,      aggraw,                      SVC);
    k_gather<<<(NODE * 64 + 255) / 256, 256, 0, stream>>>(
        feat_inst, esrc, off + 50000,  nrm + 350000, nrm + 50000,  aggraw + (size_t)50000 * 128,  NODE);
    k_gather<<<(INST * 64 + 255) / 256, 256, 0, stream>>>(
        feat_node, esrc, off + 100000, nrm + 450000, nrm + 100000, aggraw + (size_t)100000 * 128, INST);
    k_gather<<<(INST * 64 + 255) / 256, 256, 0, stream>>>(
        feat_inst, esrc, off + 200000, nrm + 500000, nrm + 200000, aggraw + (size_t)200000 * 128, INST);

    // act (in-place): lrelu(aggraw @ W + b)
    k_proj<false><<<(SVC + 63) / 64, 256, 0, stream>>>(
        aggraw, W_sc, b_sc, nullptr, nullptr, nullptr, aggraw, SVC);
    k_proj<false><<<(NODE + 63) / 64, 256, 0, stream>>>(
        aggraw + (size_t)50000 * 128, W_in, b_in, nullptr, nullptr, nullptr,
        aggraw + (size_t)50000 * 128, NODE);
    k_proj<true><<<(INST + 63) / 64, 256, 0, stream>>>(
        aggraw + (size_t)100000 * 128, W_ni, b_ni,
        aggraw + (size_t)200000 * 128, W_ii, b_ii,
        aggraw + (size_t)100000 * 128, INST);

    // out = W_tot @ act + b_tot
    k_gemm<<<(KTOT + GK - 1) / GK, 512, 0, stream>>>(aggraw, W_tot, oacc);
    k_bias<<<128, 256, 0, stream>>>(oacc, b_tot, out);
}

// Round 3
// 1096.612 us; speedup vs baseline: 3.5401x; 1.6683x over previous
//
#include <hip/hip_runtime.h>
#include <hip/hip_bf16.h>

#define SVC   50000
#define INST  100000
#define NODE  50000
#define FDIM  128
#define HDIM  128
#define OUTD  256
#define E_SC  400000
#define E_IN  100000
#define E_NI  100000
#define E_II  800000
#define NTOT  (SVC + NODE + INST)   // 200000
#define KTOT  NTOT
#define NDST  300000
#define NB    ((NDST + 255) / 256)
#define ETOT  (E_SC + E_IN + E_NI + E_II)  // 1.4M
#define GK    800                   // k per gemm block; 250 * 800 = 200000 exactly
#define NBLK  250

// ---------------- degree count ----------------
__global__ void k_deg(const int* __restrict__ src, const int* __restrict__ dst,
                      int* __restrict__ dout, int* __restrict__ din, int E) {
    int t = blockIdx.x * blockDim.x + threadIdx.x;
    if (t >= E) return;
    atomicAdd(&dout[src[t]], 1);
    atomicAdd(&din[dst[t]], 1);
}

__global__ void k_norm(const int* __restrict__ deg, float* __restrict__ nrm, int n) {
    int t = blockIdx.x * blockDim.x + threadIdx.x;
    if (t >= n) return;
    float d = (float)deg[t];
    nrm[t] = rsqrtf(d > 1.f ? d : 1.f);
}

// ---------------- scan stage 1 ----------------
__global__ void k_bsum(const int* __restrict__ din, int* __restrict__ bsum, int n) {
    __shared__ int sm[256];
    int i = blockIdx.x * 256 + threadIdx.x;
    sm[threadIdx.x] = (i < n) ? din[i] : 0;
    __syncthreads();
#pragma unroll
    for (int s = 128; s > 0; s >>= 1) {
        if (threadIdx.x < s) sm[threadIdx.x] += sm[threadIdx.x + s];
        __syncthreads();
    }
    if (threadIdx.x == 0) bsum[blockIdx.x] = sm[0];
}

// ---------------- scan stage 2 ----------------
__global__ __launch_bounds__(1024) void k_btop(const int* __restrict__ bsum,
                                               int* __restrict__ boff, int nb) {
    __shared__ int sm[1024];
    int carry = 0;
    for (int c = 0; c < 2; c++) {
        int i = c * 1024 + threadIdx.x;
        int v = (i < nb) ? bsum[i] : 0;
        sm[threadIdx.x] = v;
        __syncthreads();
        for (int s = 1; s < 1024; s <<= 1) {
            int add = (threadIdx.x >= (unsigned)s) ? sm[threadIdx.x - s] : 0;
            __syncthreads();
            sm[threadIdx.x] += add;
            __syncthreads();
        }
        if (i < nb) boff[i] = carry + sm[threadIdx.x] - v;
        carry += sm[1023];
        __syncthreads();
    }
}

// ---------------- scan stage 3 ----------------
__global__ void k_off(const int* __restrict__ din, const int* __restrict__ boff,
                      int* __restrict__ off, int* __restrict__ cur, int n) {
    __shared__ int sm[256];
    int i = blockIdx.x * 256 + threadIdx.x;
    int v = (i < n) ? din[i] : 0;
    sm[threadIdx.x] = v;
    __syncthreads();
#pragma unroll
    for (int s = 1; s < 256; s <<= 1) {
        int add = (threadIdx.x >= (unsigned)s) ? sm[threadIdx.x - s] : 0;
        __syncthreads();
        sm[threadIdx.x] += add;
        __syncthreads();
    }
    if (i < n) {
        int o = boff[blockIdx.x] + sm[threadIdx.x] - v;
        off[i] = o;
        cur[i] = o;
    }
    if (i == 0) off[n] = ETOT;
}

// ---------------- bin edges by dst ----------------
__global__ void k_bin(const int* __restrict__ src, const int* __restrict__ dst,
                      int* __restrict__ cur, int* __restrict__ esrc, int E) {
    int t = blockIdx.x * blockDim.x + threadIdx.x;
    if (t >= E) return;
    int pos = atomicAdd(&cur[dst[t]], 1);
    esrc[pos] = src[t];
}

// ---------------- gather ----------------
__global__ __launch_bounds__(256) void k_gather(const float* __restrict__ feat,
                                                const int* __restrict__ esrc,
                                                const int* __restrict__ off,
                                                const float* __restrict__ ns,
                                                const float* __restrict__ ndv,
                                                float* __restrict__ agg, int nrows) {
    int wid = (blockIdx.x * 256 + threadIdx.x) >> 6;
    if (wid >= nrows) return;
    int lane = threadIdx.x & 63;
    int e0 = off[wid], e1 = off[wid + 1];
    float ax = 0.f, ay = 0.f;
    for (int e = e0; e < e1; e++) {
        int s = esrc[e];
        float sc = ns[s];
        float2 v = *reinterpret_cast<const float2*>(feat + (size_t)s * FDIM + lane * 2);
        ax = fmaf(v.x, sc, ax);
        ay = fmaf(v.y, sc, ay);
    }
    float nv = ndv[wid];
    *reinterpret_cast<float2*>(agg + (size_t)wid * FDIM + lane * 2) = make_float2(ax * nv, ay * nv);
}

// ---------------- projection ----------------
template <bool DUAL>
__global__ __launch_bounds__(256) void k_proj(
    const float* __restrict__ A0, const float* __restrict__ W0, const float* __restrict__ b0,
    const float* __restrict__ A1, const float* __restrict__ W1, const float* __restrict__ b1,
    float* __restrict__ out, int nrows) {
    __shared__ float xs0[64][36];
    __shared__ float ws0[32][128];
    __shared__ float xs1[DUAL ? 64 : 1][36];
    __shared__ float ws1[DUAL ? 32 : 1][128];

    const int t  = threadIdx.x;
    const int tc = t & 15;
    const int tr = t >> 4;
    const int rowbase = blockIdx.x * 64;

    float acc[4][8];
#pragma unroll
    for (int i = 0; i < 4; i++)
#pragma unroll
        for (int j = 0; j < 8; j++) acc[i][j] = 0.f;

    for (int k0 = 0; k0 < FDIM; k0 += 32) {
        __syncthreads();
#pragma unroll
        for (int p = 0; p < 4; p++) {
            int f4 = t + p * 256;
            int kr = f4 >> 5, c4 = f4 & 31;
            *reinterpret_cast<float4*>(&ws0[kr][c4 * 4]) =
                *reinterpret_cast<const float4*>(W0 + (size_t)(k0 + kr) * HDIM + c4 * 4);
            if constexpr (DUAL) {
                *reinterpret_cast<float4*>(&ws1[kr][c4 * 4]) =
                    *reinterpret_cast<const float4*>(W1 + (size_t)(k0 + kr) * HDIM + c4 * 4);
            }
        }
#pragma unroll
        for (int p = 0; p < 2; p++) {
            int f4 = t + p * 256;
            int r = f4 >> 3, kq = f4 & 7;
            int gr = rowbase + r;
            float4 v = make_float4(0.f, 0.f, 0.f, 0.f);
            if (gr < nrows) v = *reinterpret_cast<const float4*>(A0 + (size_t)gr * FDIM + k0 + kq * 4);
            *reinterpret_cast<float4*>(&xs0[r][kq * 4]) = v;
            if constexpr (DUAL) {
                float4 v1 = make_float4(0.f, 0.f, 0.f, 0.f);
                if (gr < nrows) v1 = *reinterpret_cast<const float4*>(A1 + (size_t)gr * FDIM + k0 + kq * 4);
                *reinterpret_cast<float4*>(&xs1[r][kq * 4]) = v1;
            }
        }
        __syncthreads();
#pragma unroll
        for (int kk = 0; kk < 32; kk++) {
            float wv[8];
            *reinterpret_cast<float4*>(&wv[0]) = *reinterpret_cast<const float4*>(&ws0[kk][tc * 8]);
            *reinterpret_cast<float4*>(&wv[4]) = *reinterpret_cast<const float4*>(&ws0[kk][tc * 8 + 4]);
            float xv[4];
#pragma unroll
            for (int i = 0; i < 4; i++) xv[i] = xs0[tr * 4 + i][kk];
#pragma unroll
            for (int i = 0; i < 4; i++)
#pragma unroll
                for (int j = 0; j < 8; j++) acc[i][j] = fmaf(xv[i], wv[j], acc[i][j]);
            if constexpr (DUAL) {
                float wv1[8];
                *reinterpret_cast<float4*>(&wv1[0]) = *reinterpret_cast<const float4*>(&ws1[kk][tc * 8]);
                *reinterpret_cast<float4*>(&wv1[4]) = *reinterpret_cast<const float4*>(&ws1[kk][tc * 8 + 4]);
                float xv1[4];
#pragma unroll
                for (int i = 0; i < 4; i++) xv1[i] = xs1[tr * 4 + i][kk];
#pragma unroll
                for (int i = 0; i < 4; i++)
#pragma unroll
                    for (int j = 0; j < 8; j++) acc[i][j] = fmaf(xv1[i], wv1[j], acc[i][j]);
            }
        }
    }
    float bb[8];
#pragma unroll
    for (int j = 0; j < 8; j++) {
        bb[j] = b0[tc * 8 + j];
        if constexpr (DUAL) bb[j] += b1[tc * 8 + j];
    }
#pragma unroll
    for (int i = 0; i < 4; i++) {
        int gr = rowbase + tr * 4 + i;
        if (gr < nrows) {
            float o[8];
#pragma unroll
            for (int j = 0; j < 8; j++) {
                float v = acc[i][j] + bb[j];
                o[j] = v > 0.f ? v : 0.01f * v;
            }
            float* dstp = out + (size_t)gr * HDIM + tc * 8;
            *reinterpret_cast<float4*>(dstp)     = *reinterpret_cast<const float4*>(&o[0]);
            *reinterpret_cast<float4*>(dstp + 4) = *reinterpret_cast<const float4*>(&o[4]);
        }
    }
}

// ---------------- final GEMM split-K: partials[blk] = Wt[:, kchunk] @ act[kchunk, :] ----------------
// 250 blocks x GK=800; per-block 256x128 fp32 partial tile, plain stores (no atomics).
// Register-prefetch double buffering hides global latency.
__global__ __launch_bounds__(512) void k_gemm(const float* __restrict__ act,
                                              const float* __restrict__ Wt,
                                              float* __restrict__ partials) {
    __shared__ float wsm[32][257];   // [kk][o]
    __shared__ float asm_[32][132];  // [kk][j]

    const int t  = threadIdx.x;
    const int tj = t & 15;           // j0 = tj*8
    const int to = t >> 4;           // o0 = to*8
    const int kbase = blockIdx.x * GK;

    // stage-load index mapping (constant per thread)
    // W: slots s = t + p*512, p=0..3 : o = s>>3, kq = s&7  (float4 at k=kq*4)
    // A: slots s = t + p*512, p=0..1 : kk = s>>5, j4 = s&31
    float4 rw[4], ra[2];

    // preload chunk 0
#pragma unroll
    for (int p = 0; p < 4; p++) {
        int s = t + p * 512;
        rw[p] = *reinterpret_cast<const float4*>(Wt + (size_t)(s >> 3) * KTOT + kbase + (s & 7) * 4);
    }
#pragma unroll
    for (int p = 0; p < 2; p++) {
        int s = t + p * 512;
        ra[p] = *reinterpret_cast<const float4*>(act + (size_t)(kbase + (s >> 5)) * HDIM + (s & 31) * 4);
    }

    float acc[8][8];
#pragma unroll
    for (int i = 0; i < 8; i++)
#pragma unroll
        for (int j = 0; j < 8; j++) acc[i][j] = 0.f;

    for (int kc = 0; kc < GK; kc += 32) {
        __syncthreads();
        // write prefetched regs to LDS
#pragma unroll
        for (int p = 0; p < 4; p++) {
            int s = t + p * 512;
            int o = s >> 3, kq = s & 7;
            wsm[kq * 4 + 0][o] = rw[p].x;
            wsm[kq * 4 + 1][o] = rw[p].y;
            wsm[kq * 4 + 2][o] = rw[p].z;
            wsm[kq * 4 + 3][o] = rw[p].w;
        }
#pragma unroll
        for (int p = 0; p < 2; p++) {
            int s = t + p * 512;
            *reinterpret_cast<float4*>(&asm_[s >> 5][(s & 31) * 4]) = ra[p];
        }
        __syncthreads();
        // issue next chunk's loads (consumed next iteration) — overlap with compute below
        if (kc + 32 < GK) {
            int k0n = kbase + kc + 32;
#pragma unroll
            for (int p = 0; p < 4; p++) {
                int s = t + p * 512;
                rw[p] = *reinterpret_cast<const float4*>(Wt + (size_t)(s >> 3) * KTOT + k0n + (s & 7) * 4);
            }
#pragma unroll
            for (int p = 0; p < 2; p++) {
                int s = t + p * 512;
                ra[p] = *reinterpret_cast<const float4*>(act + (size_t)(k0n + (s >> 5)) * HDIM + (s & 31) * 4);
            }
        }
#pragma unroll
        for (int kk = 0; kk < 32; kk++) {
            float av[8];
            *reinterpret_cast<float4*>(&av[0]) = *reinterpret_cast<const float4*>(&asm_[kk][tj * 8]);
            *reinterpret_cast<float4*>(&av[4]) = *reinterpret_cast<const float4*>(&asm_[kk][tj * 8 + 4]);
            float wv[8];
#pragma unroll
            for (int i = 0; i < 8; i++) wv[i] = wsm[kk][to * 8 + i];
#pragma unroll
            for (int i = 0; i < 8; i++)
#pragma unroll
                for (int j = 0; j < 8; j++) acc[i][j] = fmaf(wv[i], av[j], acc[i][j]);
        }
    }
    // plain coalesced store of this block's partial tile
    float* pt = partials + (size_t)blockIdx.x * (OUTD * HDIM);
#pragma unroll
    for (int i = 0; i < 8; i++) {
        float* row = pt + (size_t)(to * 8 + i) * HDIM + tj * 8;
        *reinterpret_cast<float4*>(row)     = make_float4(acc[i][0], acc[i][1], acc[i][2], acc[i][3]);
        *reinterpret_cast<float4*>(row + 4) = make_float4(acc[i][4], acc[i][5], acc[i][6], acc[i][7]);
    }
}

// ---------------- reduce partials + bias ----------------
__global__ __launch_bounds__(256) void k_reduce(const float* __restrict__ partials,
                                                const float* __restrict__ bt,
                                                float* __restrict__ out) {
    int i = blockIdx.x * 256 + threadIdx.x;   // 0 .. 32767
    float s = 0.f;
    for (int b = 0; b < NBLK; b++) s += partials[(size_t)b * (OUTD * HDIM) + i];
    out[i] = s + bt[i >> 7];
}

// ---------------- launch ----------------
extern "C" void kernel_launch(void* const* d_in, const int* in_sizes, int n_in,
                              void* d_out, int out_size, void* d_ws, size_t ws_size,
                              hipStream_t stream) {
    const float* feat_svc  = (const float*)d_in[0];
    const float* feat_inst = (const float*)d_in[1];
    const float* feat_node = (const float*)d_in[2];
    const int* svc_src = (const int*)d_in[3];
    const int* svc_dst = (const int*)d_in[4];
    const int* in_src  = (const int*)d_in[5];
    const int* in_dst  = (const int*)d_in[6];
    const int* ni_src  = (const int*)d_in[7];
    const int* ni_dst  = (const int*)d_in[8];
    const int* ii_src  = (const int*)d_in[9];
    const int* ii_dst  = (const int*)d_in[10];
    const float* W_sc = (const float*)d_in[11];
    const float* b_sc = (const float*)d_in[12];
    const float* W_in = (const float*)d_in[13];
    const float* b_in = (const float*)d_in[14];
    const float* W_ni = (const float*)d_in[15];
    const float* b_ni = (const float*)d_in[16];
    const float* W_ii = (const float*)d_in[17];
    const float* b_ii = (const float*)d_in[18];
    const float* W_tot = (const float*)d_in[19];
    const float* b_tot = (const float*)d_in[20];
    float* out = (float*)d_out;

    char* ws = (char*)d_ws;
    int*   deg    = (int*)ws;                          // 600000 ints
    float* nrm    = (float*)(ws + 2400000);            // 600000 f
    int*   off    = (int*)(ws + 4800000);              // 300001 ints
    int*   cur    = (int*)(ws + 6000128);              // 300000 ints
    int*   bsum   = (int*)(ws + 7200128);              // NB ints
    int*   boff   = (int*)(ws + 7205248);              // NB ints
    int*   esrc   = (int*)(ws + 7210496);              // 1.4M ints
    float* aggraw = (float*)(ws + 12810496);           // 300000*128 f
    // partials overlay the dead ii region of aggraw (rows 200000..300000, 51.2MB >= 32.8MB)
    float* partials = aggraw + (size_t)200000 * 128;

    hipMemsetAsync(deg, 0, 2400000, stream);

    k_deg<<<(E_SC + 255) / 256, 256, 0, stream>>>(svc_src, svc_dst, deg + 300000, deg + 0,      E_SC);
    k_deg<<<(E_IN + 255) / 256, 256, 0, stream>>>(in_src,  in_dst,  deg + 350000, deg + 50000,  E_IN);
    k_deg<<<(E_NI + 255) / 256, 256, 0, stream>>>(ni_src,  ni_dst,  deg + 450000, deg + 100000, E_NI);
    k_deg<<<(E_II + 255) / 256, 256, 0, stream>>>(ii_src,  ii_dst,  deg + 500000, deg + 200000, E_II);
    k_norm<<<(600000 + 255) / 256, 256, 0, stream>>>(deg, nrm, 600000);

    k_bsum<<<NB, 256, 0, stream>>>(deg, bsum, NDST);
    k_btop<<<1, 1024, 0, stream>>>(bsum, boff, NB);
    k_off<<<NB, 256, 0, stream>>>(deg, boff, off, cur, NDST);

    k_bin<<<(E_SC + 255) / 256, 256, 0, stream>>>(svc_src, svc_dst, cur + 0,      esrc, E_SC);
    k_bin<<<(E_IN + 255) / 256, 256, 0, stream>>>(in_src,  in_dst,  cur + 50000,  esrc, E_IN);
    k_bin<<<(E_NI + 255) / 256, 256, 0, stream>>>(ni_src,  ni_dst,  cur + 100000, esrc, E_NI);
    k_bin<<<(E_II + 255) / 256, 256, 0, stream>>>(ii_src,  ii_dst,  cur + 200000, esrc, E_II);

    k_gather<<<(SVC  * 64 + 255) / 256, 256, 0, stream>>>(
        feat_svc,  esrc, off + 0,      nrm + 300000, nrm + 0,      aggraw,                        SVC);
    k_gather<<<(NODE * 64 + 255) / 256, 256, 0, stream>>>(
        feat_inst, esrc, off + 50000,  nrm + 350000, nrm + 50000,  aggraw + (size_t)50000 * 128,  NODE);
    k_gather<<<(INST * 64 + 255) / 256, 256, 0, stream>>>(
        feat_node, esrc, off + 100000, nrm + 450000, nrm + 100000, aggraw + (size_t)100000 * 128, INST);
    k_gather<<<(INST * 64 + 255) / 256, 256, 0, stream>>>(
        feat_inst, esrc, off + 200000, nrm + 500000, nrm + 200000, aggraw + (size_t)200000 * 128, INST);

    k_proj<false><<<(SVC + 63) / 64, 256, 0, stream>>>(
        aggraw, W_sc, b_sc, nullptr, nullptr, nullptr, aggraw, SVC);
    k_proj<false><<<(NODE + 63) / 64, 256, 0, stream>>>(
        aggraw + (size_t)50000 * 128, W_in, b_in, nullptr, nullptr, nullptr,
        aggraw + (size_t)50000 * 128, NODE);
    k_proj<true><<<(INST + 63) / 64, 256, 0, stream>>>(
        aggraw + (size_t)100000 * 128, W_ni, b_ni,
        aggraw + (size_t)200000 * 128, W_ii, b_ii,
        aggraw + (size_t)100000 * 128, INST);

    // out = W_tot @ act + b_tot   (split-K partials, then reduce)
    k_gemm<<<NBLK, 512, 0, stream>>>(aggraw, W_tot, partials);
    k_reduce<<<(OUTD * HDIM) / 256, 256, 0, stream>>>(partials, b_tot, out);
}

// Round 5
// 961.224 us; speedup vs baseline: 4.0388x; 1.1408x over previous
//
#include <hip/hip_runtime.h>
#include <hip/hip_bf16.h>

#define SVC   50000
#define INST  100000
#define NODE  50000
#define FDIM  128
#define HDIM  128
#define OUTD  256
#define E_SC  400000
#define E_IN  100000
#define E_NI  100000
#define E_II  800000
#define NDST  300000
#define NB    ((NDST + 255) / 256)
#define ETOT  (E_SC + E_IN + E_NI + E_II)  // 1.4M

// padded region layout in aggraw (rows of 128 fp32 = 512 B):
//   svc  @ 0       P=50176 (real 50000)
//   node @ 50176   P=50176 (real 50000)
//   ni   @ 100352  P=100096 (real 100000)
//   ii   @ 200448  P=100096 (real 100000)   <- K-partner of ni (cat), partials overlay here later
#define P_SVC   50176
#define R_NODE  50176
#define R_NI    100352
#define R_II    200448
#define AGGROWS 300544
#define KPAD    200448            // actF padded k-extent (= R_II)
#define GKG     800               // k per gemm block (25 chunks of 32)
#define NBK     256               // 256*800 = 204800 >= KPAD (guarded)

typedef __attribute__((ext_vector_type(8))) short s16x8;
typedef __attribute__((ext_vector_type(4))) float f32x4;

// ---------------- degree count ----------------
__global__ void k_deg(const int* __restrict__ src, const int* __restrict__ dst,
                      int* __restrict__ dout, int* __restrict__ din, int E) {
    int t = blockIdx.x * blockDim.x + threadIdx.x;
    if (t >= E) return;
    atomicAdd(&dout[src[t]], 1);
    atomicAdd(&din[dst[t]], 1);
}

__global__ void k_norm(const int* __restrict__ deg, float* __restrict__ nrm, int n) {
    int t = blockIdx.x * blockDim.x + threadIdx.x;
    if (t >= n) return;
    float d = (float)deg[t];
    nrm[t] = rsqrtf(d > 1.f ? d : 1.f);
}

// ---------------- scan ----------------
__global__ void k_bsum(const int* __restrict__ din, int* __restrict__ bsum, int n) {
    __shared__ int sm[256];
    int i = blockIdx.x * 256 + threadIdx.x;
    sm[threadIdx.x] = (i < n) ? din[i] : 0;
    __syncthreads();
#pragma unroll
    for (int s = 128; s > 0; s >>= 1) {
        if (threadIdx.x < s) sm[threadIdx.x] += sm[threadIdx.x + s];
        __syncthreads();
    }
    if (threadIdx.x == 0) bsum[blockIdx.x] = sm[0];
}

__global__ __launch_bounds__(1024) void k_btop(const int* __restrict__ bsum,
                                               int* __restrict__ boff, int nb) {
    __shared__ int sm[1024];
    int carry = 0;
    for (int c = 0; c < 2; c++) {
        int i = c * 1024 + threadIdx.x;
        int v = (i < nb) ? bsum[i] : 0;
        sm[threadIdx.x] = v;
        __syncthreads();
        for (int s = 1; s < 1024; s <<= 1) {
            int add = (threadIdx.x >= (unsigned)s) ? sm[threadIdx.x - s] : 0;
            __syncthreads();
            sm[threadIdx.x] += add;
            __syncthreads();
        }
        if (i < nb) boff[i] = carry + sm[threadIdx.x] - v;
        carry += sm[1023];
        __syncthreads();
    }
}

__global__ void k_off(const int* __restrict__ din, const int* __restrict__ boff,
                      int* __restrict__ off, int* __restrict__ cur, int n) {
    __shared__ int sm[256];
    int i = blockIdx.x * 256 + threadIdx.x;
    int v = (i < n) ? din[i] : 0;
    sm[threadIdx.x] = v;
    __syncthreads();
#pragma unroll
    for (int s = 1; s < 256; s <<= 1) {
        int add = (threadIdx.x >= (unsigned)s) ? sm[threadIdx.x - s] : 0;
        __syncthreads();
        sm[threadIdx.x] += add;
        __syncthreads();
    }
    if (i < n) {
        int o = boff[blockIdx.x] + sm[threadIdx.x] - v;
        off[i] = o;
        cur[i] = o;
    }
    if (i == 0) off[n] = ETOT;
}

__global__ void k_bin(const int* __restrict__ src, const int* __restrict__ dst,
                      int* __restrict__ cur, int* __restrict__ esrc, int E) {
    int t = blockIdx.x * blockDim.x + threadIdx.x;
    if (t >= E) return;
    int pos = atomicAdd(&cur[dst[t]], 1);
    esrc[pos] = src[t];
}

// ---------------- gather ----------------
__global__ __launch_bounds__(256) void k_gather(const float* __restrict__ feat,
                                                const int* __restrict__ esrc,
                                                const int* __restrict__ off,
                                                const float* __restrict__ ns,
                                                const float* __restrict__ ndv,
                                                float* __restrict__ agg, int nrows) {
    int wid = (blockIdx.x * 256 + threadIdx.x) >> 6;
    if (wid >= nrows) return;
    int lane = threadIdx.x & 63;
    int e0 = off[wid], e1 = off[wid + 1];
    float ax = 0.f, ay = 0.f;
    for (int e = e0; e < e1; e++) {
        int s = esrc[e];
        float sc = ns[s];
        float2 v = *reinterpret_cast<const float2*>(feat + (size_t)s * FDIM + lane * 2);
        ax = fmaf(v.x, sc, ax);
        ay = fmaf(v.y, sc, ay);
    }
    float nv = ndv[wid];
    *reinterpret_cast<float2*>(agg + (size_t)wid * FDIM + lane * 2) = make_float2(ax * nv, ay * nv);
}

// ---------------- bf16 hi/lo helpers ----------------
__device__ __forceinline__ uint2 pack_hi(float4 v) {
    uint2 r;
    r.x = (__float_as_uint(v.x) >> 16) | (__float_as_uint(v.y) & 0xFFFF0000u);
    r.y = (__float_as_uint(v.z) >> 16) | (__float_as_uint(v.w) & 0xFFFF0000u);
    return r;
}
__device__ __forceinline__ float bresid(float x) {
    return x - __uint_as_float(__float_as_uint(x) & 0xFFFF0000u);
}
__device__ __forceinline__ uint2 pack_lo(float4 v) {
    return pack_hi(make_float4(bresid(v.x), bresid(v.y), bresid(v.z), bresid(v.w)));
}

// ---------------- weight fragment prep ----------------
// Wfrag layout per weight-set: [half(hi,lo)][chunk][asub 8][lane 64][8 bf16]
// element: W[k = ch*32 + 8*(l>>4)+i][n = asub*16 + (l&15)]
__global__ __launch_bounds__(256) void k_prep(const float* __restrict__ Wsc, const float* __restrict__ Win,
                                              const float* __restrict__ Wni, const float* __restrict__ Wii,
                                              const float* __restrict__ bni, const float* __restrict__ bii,
                                              char* __restrict__ wf, float* __restrict__ bcat) {
    __shared__ float Ws[128 * 128];
    int part = blockIdx.x;  // 0 sc, 1 in, 2 ni, 3 ii
    const float* W = (part == 0) ? Wsc : (part == 1) ? Win : (part == 2) ? Wni : Wii;
    char* dst = (part == 0) ? wf : (part == 1) ? wf + 65536 : wf + 131072;
    size_t halfsz = (part < 2) ? 32768 : 65536;
    int choff = (part == 3) ? 4 : 0;
    int t = threadIdx.x;
    for (int i = t; i < 4096; i += 256)
        ((float4*)Ws)[i] = ((const float4*)W)[i];
    __syncthreads();
    for (int slot = t; slot < 2048; slot += 256) {
        int ch = slot >> 9;
        int asub = (slot >> 6) & 7;
        int l = slot & 63;
        int n = (asub << 4) + (l & 15);
        int kb = (ch << 5) + ((l >> 4) << 3);
        uint4 hi, lo;
        unsigned hh[8], ll[8];
#pragma unroll
        for (int i = 0; i < 8; i++) {
            float x = Ws[(kb + i) * 128 + n];
            unsigned b = __float_as_uint(x);
            hh[i] = b >> 16;
            float r = x - __uint_as_float(b & 0xFFFF0000u);
            ll[i] = __float_as_uint(r) >> 16;
        }
        hi.x = hh[0] | (hh[1] << 16); hi.y = hh[2] | (hh[3] << 16);
        hi.z = hh[4] | (hh[5] << 16); hi.w = hh[6] | (hh[7] << 16);
        lo.x = ll[0] | (ll[1] << 16); lo.y = ll[2] | (ll[3] << 16);
        lo.z = ll[4] | (ll[5] << 16); lo.w = ll[6] | (ll[7] << 16);
        size_t o = (size_t)((((choff + ch) << 3) + asub) * 64 + l) << 4;
        *(uint4*)(dst + o) = hi;
        *(uint4*)(dst + halfsz + o) = lo;
    }
    if (part == 3 && t < 128) bcat[t] = bni[t] + bii[t];
}

// ---------------- unified MFMA GEMM: tile [128 M][256 cols], 8 waves, K-chunks of 32 ----------------
// MODE 0 (proj): M=n, cols=r.  actF(n,r) = lrelu(sum_k W[k][n]*agg[r][k] + bias[n]) -> bf16 hi/lo tile
// MODE 1 (gemm): M=j, cols=o.  partial(j,o) = sum_k actF(j,kpad)*Wt[o][klogical]
template <int MODE>
__global__ __launch_bounds__(512) void k_mm(
    const float* __restrict__ B0, const float* __restrict__ B1, int nch,
    const char* __restrict__ wfA, int halfsz, const float* __restrict__ bias,
    int nreal, int pbase,
    char* __restrict__ agb, const float* __restrict__ Wt, float* __restrict__ partials) {
    __shared__ uint4 smem4[3072];           // 48 KB: A hi 8K | A lo 8K | B hi 16K | B lo 16K
    char* smem = (char*)smem4;
    char* Ab = smem;
    char* Bb = smem + 16384;

    const int t = threadIdx.x;
    const int l = t & 63;
    const int w = t >> 6;
    const int blk = blockIdx.x;
    const int r0p = blk << 8;                 // proj: local padded row base
    const size_t kbase = (size_t)blk * GKG;   // gemm: padded k base

    f32x4 acc[2][8];
#pragma unroll
    for (int a = 0; a < 2; a++)
#pragma unroll
        for (int m = 0; m < 8; m++) acc[a][m] = (f32x4){0.f, 0.f, 0.f, 0.f};

    const int nchunks = (MODE == 0) ? nch : (GKG / 32);
    for (int ch = 0; ch < nchunks; ch++) {
        // -------- stage B: cols c 0..255, k 0..31 --------
#pragma unroll
        for (int p = 0; p < 4; p++) {
            int s = t + (p << 9);
            int c = s >> 3, kq = s & 7;
            float4 v;
            if (MODE == 0) {
                const float* bp = (ch < 4) ? B0 : B1;
                v = *(const float4*)(bp + (size_t)(r0p + c) * 128 + ((ch & 3) << 5) + (kq << 2));
            } else {
                // padded k -> logical cat k (segment map); pad rows -> 0
                size_t kg = kbase + (ch << 5) + (kq << 2);
                long lk = -1;
                if (kg < 50000) lk = (long)kg;
                else if (kg >= 50176 && kg < 100176) lk = (long)kg - 176;
                else if (kg >= 100352 && kg < 200352) lk = (long)kg - 352;
                v = (lk >= 0) ? *(const float4*)(Wt + (size_t)c * 200000 + lk)
                              : make_float4(0.f, 0.f, 0.f, 0.f);
            }
            int db = ((c >> 4) << 10) + (((c & 15) + ((kq >> 1) << 4)) << 4) + ((kq & 1) << 3);
            *(uint2*)(Bb + db) = pack_hi(v);
            *(uint2*)(Bb + 16384 + db) = pack_lo(v);
        }
        // -------- stage A: wave w covers asub = w, both halves --------
#pragma unroll
        for (int half = 0; half < 2; half++) {
            uint4 av = (uint4){0u, 0u, 0u, 0u};
            if (MODE == 0) {
                av = *(const uint4*)(wfA + (size_t)half * halfsz +
                                     ((size_t)((((ch << 3) + w) << 6) + l) << 4));
            } else {
                size_t kg = kbase + (ch << 5) + ((l >> 4) << 3);
                if (kg < KPAD) {
                    int j = (w << 4) + (l & 15);
                    av = *(const uint4*)(agb + (kg >> 8) * 131072 + (size_t)half * 65536 +
                                         ((size_t)((j << 8) + (int)(kg & 255)) << 1));
                }
            }
            *(uint4*)(Ab + (half << 13) + (w << 10) + (l << 4)) = av;
        }
        __syncthreads();
        // -------- compute --------
        s16x8 ah[2], al[2];
#pragma unroll
        for (int nn = 0; nn < 2; nn++) {
            int asub = ((w & 3) << 1) + nn;
            ah[nn] = *(const s16x8*)(Ab + (asub << 10) + (l << 4));
            al[nn] = *(const s16x8*)(Ab + 8192 + (asub << 10) + (l << 4));
        }
#pragma unroll
        for (int m = 0; m < 8; m++) {
            int ms = ((w >> 2) << 3) + m;
            s16x8 bh = *(const s16x8*)(Bb + (ms << 10) + (l << 4));
            s16x8 bl = *(const s16x8*)(Bb + 16384 + (ms << 10) + (l << 4));
#pragma unroll
            for (int nn = 0; nn < 2; nn++) {
                acc[nn][m] = __builtin_amdgcn_mfma_f32_16x16x32_bf16(ah[nn], bh, acc[nn][m], 0, 0, 0);
                acc[nn][m] = __builtin_amdgcn_mfma_f32_16x16x32_bf16(ah[nn], bl, acc[nn][m], 0, 0, 0);
                acc[nn][m] = __builtin_amdgcn_mfma_f32_16x16x32_bf16(al[nn], bh, acc[nn][m], 0, 0, 0);
            }
        }
        __syncthreads();
    }
    // -------- epilogue --------
    if (MODE == 0) {
        char* tile = agb + (((size_t)pbase + (size_t)r0p) << 9);   // this block's 256-row actF tile
        float bv[2][4];
#pragma unroll
        for (int nn = 0; nn < 2; nn++)
#pragma unroll
            for (int q = 0; q < 4; q++)
                bv[nn][q] = bias[((w & 3) << 5) + (nn << 4) + ((l >> 4) << 2) + q];
#pragma unroll
        for (int nn = 0; nn < 2; nn++) {
#pragma unroll
            for (int m = 0; m < 8; m++) {
                int rl = ((w >> 2) << 7) + (m << 4) + (l & 15);
                bool ok = (r0p + rl) < nreal;
#pragma unroll
                for (int q = 0; q < 4; q++) {
                    int n = ((w & 3) << 5) + (nn << 4) + ((l >> 4) << 2) + q;
                    float v = acc[nn][m][q] + bv[nn][q];
                    v = v > 0.f ? v : 0.01f * v;
                    unsigned b = __float_as_uint(v);
                    ushort h = ok ? (ushort)(b >> 16) : (ushort)0;
                    float r = v - __uint_as_float(b & 0xFFFF0000u);
                    ushort lo2 = ok ? (ushort)(__float_as_uint(r) >> 16) : (ushort)0;
                    *(ushort*)(tile + (((n << 8) + rl) << 1)) = h;
                    *(ushort*)(tile + 65536 + (((n << 8) + rl) << 1)) = lo2;
                }
            }
        }
    } else {
        float* pt = partials + (size_t)blk * 32768;
#pragma unroll
        for (int nn = 0; nn < 2; nn++) {
#pragma unroll
            for (int m = 0; m < 8; m++) {
                int o = ((w >> 2) << 7) + (m << 4) + (l & 15);
#pragma unroll
                for (int q = 0; q < 4; q++) {
                    int j = ((w & 3) << 5) + (nn << 4) + ((l >> 4) << 2) + q;
                    pt[(j << 8) + o] = acc[nn][m][q];
                }
            }
        }
    }
}

// ---------------- reduce partials + bias, transpose to out[o][j] ----------------
__global__ __launch_bounds__(256) void k_reduce(const float* __restrict__ partials,
                                                const float* __restrict__ bt,
                                                float* __restrict__ out) {
    int i = blockIdx.x * 256 + threadIdx.x;   // i = j*256 + o
    float s = 0.f;
    for (int b = 0; b < NBK; b++) s += partials[(size_t)b * 32768 + i];
    int j = i >> 8, o = i & 255;
    out[(o << 7) + j] = s + bt[o];
}

// ---------------- launch ----------------
extern "C" void kernel_launch(void* const* d_in, const int* in_sizes, int n_in,
                              void* d_out, int out_size, void* d_ws, size_t ws_size,
                              hipStream_t stream) {
    const float* feat_svc  = (const float*)d_in[0];
    const float* feat_inst = (const float*)d_in[1];
    const float* feat_node = (const float*)d_in[2];
    const int* svc_src = (const int*)d_in[3];
    const int* svc_dst = (const int*)d_in[4];
    const int* in_src  = (const int*)d_in[5];
    const int* in_dst  = (const int*)d_in[6];
    const int* ni_src  = (const int*)d_in[7];
    const int* ni_dst  = (const int*)d_in[8];
    const int* ii_src  = (const int*)d_in[9];
    const int* ii_dst  = (const int*)d_in[10];
    const float* W_sc = (const float*)d_in[11];
    const float* b_sc = (const float*)d_in[12];
    const float* W_in = (const float*)d_in[13];
    const float* b_in = (const float*)d_in[14];
    const float* W_ni = (const float*)d_in[15];
    const float* b_ni = (const float*)d_in[16];
    const float* W_ii = (const float*)d_in[17];
    const float* b_ii = (const float*)d_in[18];
    const float* W_tot = (const float*)d_in[19];
    const float* b_tot = (const float*)d_in[20];
    float* out = (float*)d_out;

    char* ws = (char*)d_ws;
    int*   deg  = (int*)ws;                      // 600000 ints
    float* nrm  = (float*)(ws + 2400000);        // 600000 f
    int*   off  = (int*)(ws + 4800000);          // 300001 ints
    int*   cur  = (int*)(ws + 6000128);          // 300000 ints (dead after bin -> Wfrag)
    char*  wf   = ws + 6000128;                  // 256 KB frag weights (overlays cur)
    float* bcat = (float*)(ws + 6262272);        // 128 f
    int*   bsum = (int*)(ws + 7200128);
    int*   boff = (int*)(ws + 7205248);
    int*   esrc = (int*)(ws + 7210496);          // 1.4M ints
    float* aggraw = (float*)(ws + 12810496);     // AGGROWS*128 f (300544 rows)
    char*  aggb   = ws + 12810496;
    float* partials = (float*)(ws + 12810496 + (size_t)R_II * 512);  // overlays dead ii region (33.5MB < 51.2MB)

    hipMemsetAsync(deg, 0, 2400000, stream);

    k_deg<<<(E_SC + 255) / 256, 256, 0, stream>>>(svc_src, svc_dst, deg + 300000, deg + 0,      E_SC);
    k_deg<<<(E_IN + 255) / 256, 256, 0, stream>>>(in_src,  in_dst,  deg + 350000, deg + 50000,  E_IN);
    k_deg<<<(E_NI + 255) / 256, 256, 0, stream>>>(ni_src,  ni_dst,  deg + 450000, deg + 100000, E_NI);
    k_deg<<<(E_II + 255) / 256, 256, 0, stream>>>(ii_src,  ii_dst,  deg + 500000, deg + 200000, E_II);
    k_norm<<<(600000 + 255) / 256, 256, 0, stream>>>(deg, nrm, 600000);

    k_bsum<<<NB, 256, 0, stream>>>(deg, bsum, NDST);
    k_btop<<<1, 1024, 0, stream>>>(bsum, boff, NB);
    k_off<<<NB, 256, 0, stream>>>(deg, boff, off, cur, NDST);

    k_bin<<<(E_SC + 255) / 256, 256, 0, stream>>>(svc_src, svc_dst, cur + 0,      esrc, E_SC);
    k_bin<<<(E_IN + 255) / 256, 256, 0, stream>>>(in_src,  in_dst,  cur + 50000,  esrc, E_IN);
    k_bin<<<(E_NI + 255) / 256, 256, 0, stream>>>(ni_src,  ni_dst,  cur + 100000, esrc, E_NI);
    k_bin<<<(E_II + 255) / 256, 256, 0, stream>>>(ii_src,  ii_dst,  cur + 200000, esrc, E_II);

    // weights -> fragment order (cur is dead now)
    k_prep<<<4, 256, 0, stream>>>(W_sc, W_in, W_ni, W_ii, b_ni, b_ii, wf, bcat);

    // gather into padded regions
    k_gather<<<(SVC  * 64 + 255) / 256, 256, 0, stream>>>(
        feat_svc,  esrc, off + 0,      nrm + 300000, nrm + 0,      aggraw,                         SVC);
    k_gather<<<(NODE * 64 + 255) / 256, 256, 0, stream>>>(
        feat_inst, esrc, off + 50000,  nrm + 350000, nrm + 50000,  aggraw + (size_t)R_NODE * 128,  NODE);
    k_gather<<<(INST * 64 + 255) / 256, 256, 0, stream>>>(
        feat_node, esrc, off + 100000, nrm + 450000, nrm + 100000, aggraw + (size_t)R_NI * 128,    INST);
    k_gather<<<(INST * 64 + 255) / 256, 256, 0, stream>>>(
        feat_inst, esrc, off + 200000, nrm + 500000, nrm + 200000, aggraw + (size_t)R_II * 128,    INST);

    // projections -> actF (bf16 hi/lo tiles overlaid on aggraw, in-place per block)
    k_mm<0><<<196, 512, 0, stream>>>(aggraw, aggraw, 4,
                                     wf, 32768, b_sc, 50000, 0,
                                     aggb, nullptr, nullptr);
    k_mm<0><<<196, 512, 0, stream>>>(aggraw + (size_t)R_NODE * 128, aggraw + (size_t)R_NODE * 128, 4,
                                     wf + 65536, 32768, b_in, 50000, R_NODE,
                                     aggb, nullptr, nullptr);
    k_mm<0><<<391, 512, 0, stream>>>(aggraw + (size_t)R_NI * 128, aggraw + (size_t)R_II * 128, 8,
                                     wf + 131072, 65536, bcat, 100000, R_NI,
                                     aggb, nullptr, nullptr);

    // final GEMM (split-K partials) + reduce
    k_mm<1><<<NBK, 512, 0, stream>>>(nullptr, nullptr, 0,
                                     nullptr, 0, nullptr, 0, 0,
                                     aggb, W_tot, partials);
    k_reduce<<<128, 256, 0, stream>>>(partials, b_tot, out);
}

// Round 6
// 904.754 us; speedup vs baseline: 4.2908x; 1.0624x over previous
//
#include <hip/hip_runtime.h>
#include <hip/hip_bf16.h>

#define SVC   50000
#define INST  100000
#define NODE  50000
#define FDIM  128
#define HDIM  128
#define OUTD  256
#define E_SC  400000
#define E_IN  100000
#define E_NI  100000
#define E_II  800000
#define NDST  300000
#define NB    ((NDST + 255) / 256)
#define ETOT  (E_SC + E_IN + E_NI + E_II)  // 1.4M

// padded region layout in aggraw (rows of 128 fp32 = 512 B):
#define P_SVC   50176
#define R_NODE  50176
#define R_NI    100352
#define R_II    200448
#define AGGROWS 300544
#define KPAD    200448            // actF padded k-extent (= R_II)
#define GKG     800               // k per gemm block (25 chunks of 32)
#define NBK     256               // 256*800 = 204800 >= KPAD (guarded)

typedef __attribute__((ext_vector_type(8))) short s16x8;
typedef __attribute__((ext_vector_type(4))) float f32x4;

// ---------------- fused degree count (all 4 relations) ----------------
__global__ void k_deg_all(const int* __restrict__ s0, const int* __restrict__ d0,
                          const int* __restrict__ s1, const int* __restrict__ d1,
                          const int* __restrict__ s2, const int* __restrict__ d2,
                          const int* __restrict__ s3, const int* __restrict__ d3,
                          int* __restrict__ deg) {
    int t = blockIdx.x * blockDim.x + threadIdx.x;
    const int* src; const int* dst; int e, so, dd;
    if (t < E_SC)                    { src = s0; dst = d0; e = t;                       so = 300000; dd = 0; }
    else if (t < E_SC + E_IN)        { src = s1; dst = d1; e = t - E_SC;                so = 350000; dd = 50000; }
    else if (t < E_SC + E_IN + E_NI) { src = s2; dst = d2; e = t - (E_SC + E_IN);       so = 450000; dd = 100000; }
    else if (t < ETOT)               { src = s3; dst = d3; e = t - (E_SC + E_IN + E_NI); so = 500000; dd = 200000; }
    else return;
    atomicAdd(&deg[so + src[e]], 1);
    atomicAdd(&deg[dd + dst[e]], 1);
}

__global__ void k_norm(const int* __restrict__ deg, float* __restrict__ nrm, int n) {
    int t = blockIdx.x * blockDim.x + threadIdx.x;
    if (t >= n) return;
    float d = (float)deg[t];
    nrm[t] = rsqrtf(d > 1.f ? d : 1.f);
}

// ---------------- scan ----------------
__global__ void k_bsum(const int* __restrict__ din, int* __restrict__ bsum, int n) {
    __shared__ int sm[256];
    int i = blockIdx.x * 256 + threadIdx.x;
    sm[threadIdx.x] = (i < n) ? din[i] : 0;
    __syncthreads();
#pragma unroll
    for (int s = 128; s > 0; s >>= 1) {
        if (threadIdx.x < s) sm[threadIdx.x] += sm[threadIdx.x + s];
        __syncthreads();
    }
    if (threadIdx.x == 0) bsum[blockIdx.x] = sm[0];
}

__global__ __launch_bounds__(1024) void k_btop(const int* __restrict__ bsum,
                                               int* __restrict__ boff, int nb) {
    __shared__ int sm[1024];
    int carry = 0;
    for (int c = 0; c < 2; c++) {
        int i = c * 1024 + threadIdx.x;
        int v = (i < nb) ? bsum[i] : 0;
        sm[threadIdx.x] = v;
        __syncthreads();
        for (int s = 1; s < 1024; s <<= 1) {
            int add = (threadIdx.x >= (unsigned)s) ? sm[threadIdx.x - s] : 0;
            __syncthreads();
            sm[threadIdx.x] += add;
            __syncthreads();
        }
        if (i < nb) boff[i] = carry + sm[threadIdx.x] - v;
        carry += sm[1023];
        __syncthreads();
    }
}

__global__ void k_off(const int* __restrict__ din, const int* __restrict__ boff,
                      int* __restrict__ off, int* __restrict__ cur, int n) {
    __shared__ int sm[256];
    int i = blockIdx.x * 256 + threadIdx.x;
    int v = (i < n) ? din[i] : 0;
    sm[threadIdx.x] = v;
    __syncthreads();
#pragma unroll
    for (int s = 1; s < 256; s <<= 1) {
        int add = (threadIdx.x >= (unsigned)s) ? sm[threadIdx.x - s] : 0;
        __syncthreads();
        sm[threadIdx.x] += add;
        __syncthreads();
    }
    if (i < n) {
        int o = boff[blockIdx.x] + sm[threadIdx.x] - v;
        off[i] = o;
        cur[i] = o;
    }
    if (i == 0) off[n] = ETOT;
}

// ---------------- fused bin (all 4 relations) ----------------
__global__ void k_bin_all(const int* __restrict__ s0, const int* __restrict__ d0,
                          const int* __restrict__ s1, const int* __restrict__ d1,
                          const int* __restrict__ s2, const int* __restrict__ d2,
                          const int* __restrict__ s3, const int* __restrict__ d3,
                          int* __restrict__ cur, int* __restrict__ esrc) {
    int t = blockIdx.x * blockDim.x + threadIdx.x;
    const int* src; const int* dst; int e, cd;
    if (t < E_SC)                    { src = s0; dst = d0; e = t;                       cd = 0; }
    else if (t < E_SC + E_IN)        { src = s1; dst = d1; e = t - E_SC;                cd = 50000; }
    else if (t < E_SC + E_IN + E_NI) { src = s2; dst = d2; e = t - (E_SC + E_IN);       cd = 100000; }
    else if (t < ETOT)               { src = s3; dst = d3; e = t - (E_SC + E_IN + E_NI); cd = 200000; }
    else return;
    int pos = atomicAdd(&cur[cd + dst[e]], 1);
    esrc[pos] = src[e];
}

// ---------------- fused gather: one wave per dst row, all regions co-resident ----------------
__global__ __launch_bounds__(256) void k_gather_all(
    const float* __restrict__ fsvc, const float* __restrict__ finst,
    const float* __restrict__ fnode,
    const int* __restrict__ esrc, const int* __restrict__ off,
    const float* __restrict__ nrm, float* __restrict__ aggraw) {
    int wid = (blockIdx.x * 256 + threadIdx.x) >> 6;
    if (wid >= NDST) return;
    int lane = threadIdx.x & 63;
    const float* feat; int nso; size_t prow;
    if (wid < 50000)       { feat = fsvc;  nso = 300000; prow = (size_t)wid; }
    else if (wid < 100000) { feat = finst; nso = 350000; prow = (size_t)R_NODE + (wid - 50000); }
    else if (wid < 200000) { feat = fnode; nso = 450000; prow = (size_t)R_NI + (wid - 100000); }
    else                   { feat = finst; nso = 500000; prow = (size_t)R_II + (wid - 200000); }
    const float* ns = nrm + nso;
    int e0 = off[wid], e1 = off[wid + 1];
    float ax = 0.f, ay = 0.f, bx = 0.f, by = 0.f;
    int e = e0;
    for (; e + 2 <= e1; e += 2) {
        int sA = esrc[e], sB = esrc[e + 1];
        float cA = ns[sA], cB = ns[sB];
        float2 vA = *reinterpret_cast<const float2*>(feat + (size_t)sA * FDIM + lane * 2);
        float2 vB = *reinterpret_cast<const float2*>(feat + (size_t)sB * FDIM + lane * 2);
        ax = fmaf(vA.x, cA, ax); ay = fmaf(vA.y, cA, ay);
        bx = fmaf(vB.x, cB, bx); by = fmaf(vB.y, cB, by);
    }
    if (e < e1) {
        int sA = esrc[e];
        float cA = ns[sA];
        float2 vA = *reinterpret_cast<const float2*>(feat + (size_t)sA * FDIM + lane * 2);
        ax = fmaf(vA.x, cA, ax); ay = fmaf(vA.y, cA, ay);
    }
    float nv = nrm[wid];
    *reinterpret_cast<float2*>(aggraw + prow * FDIM + lane * 2) =
        make_float2((ax + bx) * nv, (ay + by) * nv);
}

// ---------------- bf16 hi/lo helpers ----------------
__device__ __forceinline__ uint2 pack_hi(float4 v) {
    uint2 r;
    r.x = (__float_as_uint(v.x) >> 16) | (__float_as_uint(v.y) & 0xFFFF0000u);
    r.y = (__float_as_uint(v.z) >> 16) | (__float_as_uint(v.w) & 0xFFFF0000u);
    return r;
}
__device__ __forceinline__ float bresid(float x) {
    return x - __uint_as_float(__float_as_uint(x) & 0xFFFF0000u);
}
__device__ __forceinline__ uint2 pack_lo(float4 v) {
    return pack_hi(make_float4(bresid(v.x), bresid(v.y), bresid(v.z), bresid(v.w)));
}

// ---------------- weight fragment prep ----------------
__global__ __launch_bounds__(256) void k_prep(const float* __restrict__ Wsc, const float* __restrict__ Win,
                                              const float* __restrict__ Wni, const float* __restrict__ Wii,
                                              const float* __restrict__ bni, const float* __restrict__ bii,
                                              char* __restrict__ wf, float* __restrict__ bcat) {
    __shared__ float Ws[128 * 128];
    int part = blockIdx.x;  // 0 sc, 1 in, 2 ni, 3 ii
    const float* W = (part == 0) ? Wsc : (part == 1) ? Win : (part == 2) ? Wni : Wii;
    char* dst = (part == 0) ? wf : (part == 1) ? wf + 65536 : wf + 131072;
    size_t halfsz = (part < 2) ? 32768 : 65536;
    int choff = (part == 3) ? 4 : 0;
    int t = threadIdx.x;
    for (int i = t; i < 4096; i += 256)
        ((float4*)Ws)[i] = ((const float4*)W)[i];
    __syncthreads();
    for (int slot = t; slot < 2048; slot += 256) {
        int ch = slot >> 9;
        int asub = (slot >> 6) & 7;
        int l = slot & 63;
        int n = (asub << 4) + (l & 15);
        int kb = (ch << 5) + ((l >> 4) << 3);
        uint4 hi, lo;
        unsigned hh[8], ll[8];
#pragma unroll
        for (int i = 0; i < 8; i++) {
            float x = Ws[(kb + i) * 128 + n];
            unsigned b = __float_as_uint(x);
            hh[i] = b >> 16;
            float r = x - __uint_as_float(b & 0xFFFF0000u);
            ll[i] = __float_as_uint(r) >> 16;
        }
        hi.x = hh[0] | (hh[1] << 16); hi.y = hh[2] | (hh[3] << 16);
        hi.z = hh[4] | (hh[5] << 16); hi.w = hh[6] | (hh[7] << 16);
        lo.x = ll[0] | (ll[1] << 16); lo.y = ll[2] | (ll[3] << 16);
        lo.z = ll[4] | (ll[5] << 16); lo.w = ll[6] | (ll[7] << 16);
        size_t o = (size_t)((((choff + ch) << 3) + asub) * 64 + l) << 4;
        *(uint4*)(dst + o) = hi;
        *(uint4*)(dst + halfsz + o) = lo;
    }
    if (part == 3 && t < 128) bcat[t] = bni[t] + bii[t];
}

// ---------------- fused projections: 783 blocks, register-prefetch double-buffered ----------------
// actF(n,r) = lrelu(sum_k W[k][n]*agg[r][k] + bias[n]) -> bf16 hi/lo tile, in-place per block
__global__ __launch_bounds__(512) void k_projall(
    const float* __restrict__ aggraw, const char* __restrict__ wf,
    const float* __restrict__ b_sc, const float* __restrict__ b_in,
    const float* __restrict__ bcat, char* __restrict__ agb) {
    __shared__ uint4 smem4[3072];           // 48 KB: A hi 8K | A lo 8K | B hi 16K | B lo 16K
    char* Ab = (char*)smem4;
    char* Bb = (char*)smem4 + 16384;

    const int t = threadIdx.x;
    const int l = t & 63;
    const int w = t >> 6;
    const int blk = blockIdx.x;

    const float *B0, *B1, *bias; const char* wfA;
    int halfsz, nch, nreal, pbase, lb;
    if (blk < 196)      { lb = blk;       B0 = aggraw;                          B1 = B0;
                          wfA = wf;           halfsz = 32768; bias = b_sc; nch = 4; nreal = 50000;  pbase = 0; }
    else if (blk < 392) { lb = blk - 196; B0 = aggraw + (size_t)R_NODE * 128;   B1 = B0;
                          wfA = wf + 65536;   halfsz = 32768; bias = b_in; nch = 4; nreal = 50000;  pbase = R_NODE; }
    else                { lb = blk - 392; B0 = aggraw + (size_t)R_NI * 128;     B1 = aggraw + (size_t)R_II * 128;
                          wfA = wf + 131072;  halfsz = 65536; bias = bcat; nch = 8; nreal = 100000; pbase = R_NI; }
    const int r0p = lb << 8;

    f32x4 acc[2][8];
#pragma unroll
    for (int a = 0; a < 2; a++)
#pragma unroll
        for (int m = 0; m < 8; m++) acc[a][m] = (f32x4){0.f, 0.f, 0.f, 0.f};

    float4 rb[4]; uint4 ra[2];
    auto loadB = [&](int ch) {
        const float* bp = (ch < 4) ? B0 : B1;
#pragma unroll
        for (int p = 0; p < 4; p++) {
            int s = t + (p << 9);
            int c = s >> 3, kq = s & 7;
            rb[p] = *(const float4*)(bp + (size_t)(r0p + c) * 128 + ((ch & 3) << 5) + (kq << 2));
        }
    };
    auto loadA = [&](int ch) {
#pragma unroll
        for (int half = 0; half < 2; half++)
            ra[half] = *(const uint4*)(wfA + (size_t)half * halfsz +
                                       ((size_t)((((ch << 3) + w) << 6) + l) << 4));
    };
    loadB(0); loadA(0);

    for (int ch = 0; ch < nch; ch++) {
        __syncthreads();
#pragma unroll
        for (int p = 0; p < 4; p++) {
            int s = t + (p << 9);
            int c = s >> 3, kq = s & 7;
            int db = ((c >> 4) << 10) + (((c & 15) + ((kq >> 1) << 4)) << 4) + ((kq & 1) << 3);
            *(uint2*)(Bb + db) = pack_hi(rb[p]);
            *(uint2*)(Bb + 16384 + db) = pack_lo(rb[p]);
        }
#pragma unroll
        for (int half = 0; half < 2; half++)
            *(uint4*)(Ab + (half << 13) + (w << 10) + (l << 4)) = ra[half];
        __syncthreads();
        if (ch + 1 < nch) { loadB(ch + 1); loadA(ch + 1); }
        s16x8 ah[2], al[2];
#pragma unroll
        for (int nn = 0; nn < 2; nn++) {
            int asub = ((w & 3) << 1) + nn;
            ah[nn] = *(const s16x8*)(Ab + (asub << 10) + (l << 4));
            al[nn] = *(const s16x8*)(Ab + 8192 + (asub << 10) + (l << 4));
        }
#pragma unroll
        for (int m = 0; m < 8; m++) {
            int ms = ((w >> 2) << 3) + m;
            s16x8 bh = *(const s16x8*)(Bb + (ms << 10) + (l << 4));
            s16x8 bl = *(const s16x8*)(Bb + 16384 + (ms << 10) + (l << 4));
#pragma unroll
            for (int nn = 0; nn < 2; nn++) {
                acc[nn][m] = __builtin_amdgcn_mfma_f32_16x16x32_bf16(ah[nn], bh, acc[nn][m], 0, 0, 0);
                acc[nn][m] = __builtin_amdgcn_mfma_f32_16x16x32_bf16(ah[nn], bl, acc[nn][m], 0, 0, 0);
                acc[nn][m] = __builtin_amdgcn_mfma_f32_16x16x32_bf16(al[nn], bh, acc[nn][m], 0, 0, 0);
            }
        }
    }
    // epilogue: bias + lrelu -> bf16 hi/lo tile (pad rows forced 0)
    char* tile = agb + (((size_t)pbase + (size_t)r0p) << 9);
    float bv[2][4];
#pragma unroll
    for (int nn = 0; nn < 2; nn++)
#pragma unroll
        for (int q = 0; q < 4; q++)
            bv[nn][q] = bias[((w & 3) << 5) + (nn << 4) + ((l >> 4) << 2) + q];
#pragma unroll
    for (int nn = 0; nn < 2; nn++) {
#pragma unroll
        for (int m = 0; m < 8; m++) {
            int rl = ((w >> 2) << 7) + (m << 4) + (l & 15);
            bool ok = (r0p + rl) < nreal;
#pragma unroll
            for (int q = 0; q < 4; q++) {
                int n = ((w & 3) << 5) + (nn << 4) + ((l >> 4) << 2) + q;
                float v = acc[nn][m][q] + bv[nn][q];
                v = v > 0.f ? v : 0.01f * v;
                unsigned b = __float_as_uint(v);
                ushort h = ok ? (ushort)(b >> 16) : (ushort)0;
                float r = v - __uint_as_float(b & 0xFFFF0000u);
                ushort lo2 = ok ? (ushort)(__float_as_uint(r) >> 16) : (ushort)0;
                *(ushort*)(tile + (((n << 8) + rl) << 1)) = h;
                *(ushort*)(tile + 65536 + (((n << 8) + rl) << 1)) = lo2;
            }
        }
    }
}

// ---------------- final GEMM split-K, register-prefetch double-buffered ----------------
// partial(j,o) = sum_k actF(j,kpad)*Wt[o][klogical]
__global__ __launch_bounds__(512) void k_gemm2(const char* __restrict__ agb,
                                               const float* __restrict__ Wt,
                                               float* __restrict__ partials) {
    __shared__ uint4 smem4[3072];
    char* Ab = (char*)smem4;
    char* Bb = (char*)smem4 + 16384;

    const int t = threadIdx.x;
    const int l = t & 63;
    const int w = t >> 6;
    const int blk = blockIdx.x;
    const size_t kbase = (size_t)blk * GKG;

    f32x4 acc[2][8];
#pragma unroll
    for (int a = 0; a < 2; a++)
#pragma unroll
        for (int m = 0; m < 8; m++) acc[a][m] = (f32x4){0.f, 0.f, 0.f, 0.f};

    float4 rb[4]; uint4 ra[2];
    auto loadB = [&](int ch) {
#pragma unroll
        for (int p = 0; p < 4; p++) {
            int s = t + (p << 9);
            int c = s >> 3, kq = s & 7;
            size_t kg = kbase + (ch << 5) + (kq << 2);
            long lk = -1;
            if (kg < 50000) lk = (long)kg;
            else if (kg >= 50176 && kg < 100176) lk = (long)kg - 176;
            else if (kg >= 100352 && kg < 200352) lk = (long)kg - 352;
            rb[p] = (lk >= 0) ? *(const float4*)(Wt + (size_t)c * 200000 + lk)
                              : make_float4(0.f, 0.f, 0.f, 0.f);
        }
    };
    auto loadA = [&](int ch) {
        size_t kg = kbase + (ch << 5) + ((l >> 4) << 3);
#pragma unroll
        for (int half = 0; half < 2; half++) {
            uint4 av = (uint4){0u, 0u, 0u, 0u};
            if (kg < KPAD) {
                int j = (w << 4) + (l & 15);
                av = *(const uint4*)(agb + (kg >> 8) * 131072 + (size_t)half * 65536 +
                                     ((size_t)((j << 8) + (int)(kg & 255)) << 1));
            }
            ra[half] = av;
        }
    };
    loadB(0); loadA(0);

    for (int ch = 0; ch < GKG / 32; ch++) {
        __syncthreads();
#pragma unroll
        for (int p = 0; p < 4; p++) {
            int s = t + (p << 9);
            int c = s >> 3, kq = s & 7;
            int db = ((c >> 4) << 10) + (((c & 15) + ((kq >> 1) << 4)) << 4) + ((kq & 1) << 3);
            *(uint2*)(Bb + db) = pack_hi(rb[p]);
            *(uint2*)(Bb + 16384 + db) = pack_lo(rb[p]);
        }
#pragma unroll
        for (int half = 0; half < 2; half++)
            *(uint4*)(Ab + (half << 13) + (w << 10) + (l << 4)) = ra[half];
        __syncthreads();
        if (ch + 1 < GKG / 32) { loadB(ch + 1); loadA(ch + 1); }
        s16x8 ah[2], al[2];
#pragma unroll
        for (int nn = 0; nn < 2; nn++) {
            int asub = ((w & 3) << 1) + nn;
            ah[nn] = *(const s16x8*)(Ab + (asub << 10) + (l << 4));
            al[nn] = *(const s16x8*)(Ab + 8192 + (asub << 10) + (l << 4));
        }
#pragma unroll
        for (int m = 0; m < 8; m++) {
            int ms = ((w >> 2) << 3) + m;
            s16x8 bh = *(const s16x8*)(Bb + (ms << 10) + (l << 4));
            s16x8 bl = *(const s16x8*)(Bb + 16384 + (ms << 10) + (l << 4));
#pragma unroll
            for (int nn = 0; nn < 2; nn++) {
                acc[nn][m] = __builtin_amdgcn_mfma_f32_16x16x32_bf16(ah[nn], bh, acc[nn][m], 0, 0, 0);
                acc[nn][m] = __builtin_amdgcn_mfma_f32_16x16x32_bf16(ah[nn], bl, acc[nn][m], 0, 0, 0);
                acc[nn][m] = __builtin_amdgcn_mfma_f32_16x16x32_bf16(al[nn], bh, acc[nn][m], 0, 0, 0);
            }
        }
    }
    float* pt = partials + (size_t)blk * 32768;
#pragma unroll
    for (int nn = 0; nn < 2; nn++) {
#pragma unroll
        for (int m = 0; m < 8; m++) {
            int o = ((w >> 2) << 7) + (m << 4) + (l & 15);
#pragma unroll
            for (int q = 0; q < 4; q++) {
                int j = ((w & 3) << 5) + (nn << 4) + ((l >> 4) << 2) + q;
                pt[(j << 8) + o] = acc[nn][m][q];
            }
        }
    }
}

// ---------------- reduce partials + bias, transpose to out[o][j] ----------------
__global__ __launch_bounds__(256) void k_reduce(const float* __restrict__ partials,
                                                const float* __restrict__ bt,
                                                float* __restrict__ out) {
    int i = blockIdx.x * 256 + threadIdx.x;   // i = j*256 + o
    float s = 0.f;
    for (int b = 0; b < NBK; b++) s += partials[(size_t)b * 32768 + i];
    int j = i >> 8, o = i & 255;
    out[(o << 7) + j] = s + bt[o];
}

// ---------------- launch ----------------
extern "C" void kernel_launch(void* const* d_in, const int* in_sizes, int n_in,
                              void* d_out, int out_size, void* d_ws, size_t ws_size,
                              hipStream_t stream) {
    const float* feat_svc  = (const float*)d_in[0];
    const float* feat_inst = (const float*)d_in[1];
    const float* feat_node = (const float*)d_in[2];
    const int* svc_src = (const int*)d_in[3];
    const int* svc_dst = (const int*)d_in[4];
    const int* in_src  = (const int*)d_in[5];
    const int* in_dst  = (const int*)d_in[6];
    const int* ni_src  = (const int*)d_in[7];
    const int* ni_dst  = (const int*)d_in[8];
    const int* ii_src  = (const int*)d_in[9];
    const int* ii_dst  = (const int*)d_in[10];
    const float* W_sc = (const float*)d_in[11];
    const float* b_sc = (const float*)d_in[12];
    const float* W_in = (const float*)d_in[13];
    const float* b_in = (const float*)d_in[14];
    const float* W_ni = (const float*)d_in[15];
    const float* b_ni = (const float*)d_in[16];
    const float* W_ii = (const float*)d_in[17];
    const float* b_ii = (const float*)d_in[18];
    const float* W_tot = (const float*)d_in[19];
    const float* b_tot = (const float*)d_in[20];
    float* out = (float*)d_out;

    char* ws = (char*)d_ws;
    int*   deg  = (int*)ws;                      // 600000 ints
    float* nrm  = (float*)(ws + 2400000);        // 600000 f
    int*   off  = (int*)(ws + 4800000);          // 300001 ints
    int*   cur  = (int*)(ws + 6000128);          // 300000 ints (dead after bin -> wf overlays)
    char*  wf   = ws + 6000128;                  // 256 KB frag weights
    float* bcat = (float*)(ws + 6262272);        // 128 f
    int*   bsum = (int*)(ws + 7200128);
    int*   boff = (int*)(ws + 7205248);
    int*   esrc = (int*)(ws + 7210496);          // 1.4M ints
    float* aggraw = (float*)(ws + 12810496);     // AGGROWS*128 f
    char*  aggb   = ws + 12810496;
    float* partials = (float*)(ws + 12810496 + (size_t)R_II * 512);  // overlays ii fp32 region

    hipMemsetAsync(deg, 0, 2400000, stream);

    k_deg_all<<<(ETOT + 255) / 256, 256, 0, stream>>>(
        svc_src, svc_dst, in_src, in_dst, ni_src, ni_dst, ii_src, ii_dst, deg);
    k_norm<<<(600000 + 255) / 256, 256, 0, stream>>>(deg, nrm, 600000);

    k_bsum<<<NB, 256, 0, stream>>>(deg, bsum, NDST);
    k_btop<<<1, 1024, 0, stream>>>(bsum, boff, NB);
    k_off<<<NB, 256, 0, stream>>>(deg, boff, off, cur, NDST);

    k_bin_all<<<(ETOT + 255) / 256, 256, 0, stream>>>(
        svc_src, svc_dst, in_src, in_dst, ni_src, ni_dst, ii_src, ii_dst, cur, esrc);

    k_prep<<<4, 256, 0, stream>>>(W_sc, W_in, W_ni, W_ii, b_ni, b_ii, wf, bcat);

    k_gather_all<<<(NDST * 64) / 256, 256, 0, stream>>>(
        feat_svc, feat_inst, feat_node, esrc, off, nrm, aggraw);

    k_projall<<<783, 512, 0, stream>>>(aggraw, wf, b_sc, b_in, bcat, aggb);

    k_gemm2<<<NBK, 512, 0, stream>>>(aggb, W_tot, partials);
    k_reduce<<<128, 256, 0, stream>>>(partials, b_tot, out);
}